// Round 13
// baseline (244.829 us; speedup 1.0000x reference)
//
#include <hip/hip_runtime.h>
#include <hip/hip_bf16.h>

#define BATCH 2
#define SEQ   2048
#define NH    16
#define NKV   4
#define HD    128
#define KDIM  2048
#define MROWS 4096
#define NQKV  3072

typedef __attribute__((ext_vector_type(8))) short  s16x8;
typedef __attribute__((ext_vector_type(4))) short  s16x4;
typedef __attribute__((ext_vector_type(4))) float  f32x4;
typedef __attribute__((ext_vector_type(16))) float f32x16;
typedef __attribute__((ext_vector_type(8))) __bf16 b16x8;

// barrier that drains LDS ops only -- leaves global prefetch loads in flight
#define BARRIER_LDS() do { \
    asm volatile("s_waitcnt lgkmcnt(0)" ::: "memory"); \
    __builtin_amdgcn_s_barrier(); \
  } while (0)

__device__ __forceinline__ unsigned short f2bf(float f) {
  __hip_bfloat16 h = __float2bfloat16(f);
  return *reinterpret_cast<unsigned short*>(&h);
}
__device__ __forceinline__ float bf2f(unsigned short h) {
  union { unsigned int u; float f; } x; x.u = ((unsigned int)h) << 16;
  return x.f;
}

__device__ __forceinline__ f32x4 MFMA16(s16x8 a, s16x8 b, f32x4 c) {
  return __builtin_amdgcn_mfma_f32_16x16x32_bf16(
      __builtin_bit_cast(b16x8, a), __builtin_bit_cast(b16x8, b), c, 0, 0, 0);
}
__device__ __forceinline__ f32x16 MFMA32(s16x8 a, s16x8 b, f32x16 c) {
  return __builtin_amdgcn_mfma_f32_32x32x16_bf16(
      __builtin_bit_cast(b16x8, a), __builtin_bit_cast(b16x8, b), c, 0, 0, 0);
}

__device__ __forceinline__ unsigned cvtpk(float lo, float hi) {
  unsigned r;
  asm("v_cvt_pk_bf16_f32 %0, %1, %2" : "=v"(r) : "v"(lo), "v"(hi));
  return r;
}
__device__ __forceinline__ void pl32swap(unsigned &d, unsigned &s) {
  asm("v_permlane32_swap_b32 %0, %1" : "+v"(d), "+v"(s));
}

__device__ __forceinline__ void gload_lds16(const void* g, void* lds) {
  __builtin_amdgcn_global_load_lds(
      (const __attribute__((address_space(1))) void*)g,
      (__attribute__((address_space(3))) void*)lds, 16, 0, 0);
}

// ---------------- fused weight prep: all 4 transposes in one launch ----------------
__global__ __launch_bounds__(256) void prep_weights(
    const float* __restrict__ Wq, const float* __restrict__ Wk,
    const float* __restrict__ Wv, const float* __restrict__ Wo,
    unsigned short* __restrict__ BT, unsigned short* __restrict__ WoT) {
  __shared__ float tile[32][33];
  int bx = blockIdx.x;
  const float* W; unsigned short* WT; int Nd, nb;
  if (bx < 64)       { W = Wq; WT = BT;                          Nd = 2048; nb = bx; }
  else if (bx < 80)  { W = Wk; WT = BT + (size_t)2048 * KDIM;    Nd = 512;  nb = bx - 64; }
  else if (bx < 96)  { W = Wv; WT = BT + (size_t)2560 * KDIM;    Nd = 512;  nb = bx - 80; }
  else               { W = Wo; WT = WoT;                         Nd = 2048; nb = bx - 96; }
  int n0 = nb * 32, k0 = blockIdx.y * 32;
  int tx = threadIdx.x & 31, ty = threadIdx.x >> 5;
#pragma unroll
  for (int i = 0; i < 4; ++i)
    tile[ty + i * 8][tx] = W[(size_t)(k0 + ty + i * 8) * Nd + n0 + tx];
  __syncthreads();
#pragma unroll
  for (int i = 0; i < 4; ++i)
    WT[(size_t)(n0 + ty + i * 8) * KDIM + k0 + tx] = f2bf(tile[tx][ty + i * 8]);
}

// ---------------- f32 -> bf16 bulk convert ----------------
__global__ __launch_bounds__(256) void conv_bf16(
    const float* __restrict__ X, unsigned short* __restrict__ Y) {
  int i = blockIdx.x * 256 + threadIdx.x;
  const float4 a = ((const float4*)X)[2 * i];
  const float4 b = ((const float4*)X)[2 * i + 1];
  s16x8 o;
  o[0] = (short)f2bf(a.x); o[1] = (short)f2bf(a.y);
  o[2] = (short)f2bf(a.z); o[3] = (short)f2bf(a.w);
  o[4] = (short)f2bf(b.x); o[5] = (short)f2bf(b.y);
  o[6] = (short)f2bf(b.z); o[7] = (short)f2bf(b.w);
  ((s16x8*)Y)[i] = o;
}

// ---------------- RoPE cos/sin table ----------------
__global__ __launch_bounds__(256) void rope_table_kernel(float* __restrict__ tbl) {
  int i = blockIdx.x * 256 + threadIdx.x;
  int s = i >> 6, j = i & 63;
  float inv = powf(10000.0f, -(float)(2 * j) * (1.0f / 128.0f));
  float f = (float)s * inv;
  tbl[2 * i]     = cosf(f);
  tbl[2 * i + 1] = sinf(f);
}

// ---------------- QKV GEMM (bf16 x bf16); per-head epilogue; XCD-swizzled grid ----------------
__global__ __launch_bounds__(256) void gemm_qkv(
    const unsigned short* __restrict__ A, const unsigned short* __restrict__ BT,
    unsigned short* __restrict__ Qo, unsigned short* __restrict__ Ko,
    unsigned short* __restrict__ Vo) {
  __shared__ __align__(16) unsigned short la[128][32];
  __shared__ __align__(16) unsigned short lb[128][32];
  int tid = threadIdx.x, lane = tid & 63, w = tid >> 6;
  int lin = blockIdx.x;
  int swz = (lin & 7) * 96 + (lin >> 3);
  int bx = swz % 24, by = swz / 24;
  int m0 = by * 128, n0 = bx * 128;
  int wr = (w >> 1) * 64, wc = (w & 1) * 64;
  int fr = lane & 15, kg = (lane >> 4) * 8, rg = (lane >> 4) * 4;
  f32x4 acc[4][4] = {};
  for (int kt = 0; kt < KDIM; kt += 32) {
    __syncthreads();
#pragma unroll
    for (int i = 0; i < 2; ++i) {
      int idx = tid + i * 256;
      int row = idx >> 2, seg = idx & 3;
      gload_lds16(A + (size_t)(m0 + row) * KDIM + kt + seg * 8,
                  (char*)la + (size_t)(i * 256 + w * 64) * 16);
      gload_lds16(BT + (size_t)(n0 + row) * KDIM + kt + seg * 8,
                  (char*)lb + (size_t)(i * 256 + w * 64) * 16);
    }
    __syncthreads();
    s16x8 af[4], bf[4];
#pragma unroll
    for (int mi = 0; mi < 4; ++mi) af[mi] = *(const s16x8*)(&la[wr + mi * 16 + fr][kg]);
#pragma unroll
    for (int ni = 0; ni < 4; ++ni) bf[ni] = *(const s16x8*)(&lb[wc + ni * 16 + fr][kg]);
#pragma unroll
    for (int mi = 0; mi < 4; ++mi)
#pragma unroll
      for (int ni = 0; ni < 4; ++ni) acc[mi][ni] = MFMA16(af[mi], bf[ni], acc[mi][ni]);
  }
  int rbase = m0 + wr + rg;
#pragma unroll
  for (int ni = 0; ni < 4; ++ni) {
    int gn = n0 + wc + ni * 16 + fr;
    if (gn < 2048) {
      int hh = gn >> 7, d = gn & 127;
#pragma unroll
      for (int mi = 0; mi < 4; ++mi)
#pragma unroll
        for (int r = 0; r < 4; ++r) {
          int grow = rbase + mi * 16 + r;
          int bb = grow >> 11, ss = grow & 2047;
          Qo[((size_t)(bb * NH + hh) * SEQ + ss) * HD + d] = f2bf(acc[mi][ni][r]);
        }
    } else if (gn < 2560) {
      int c = gn - 2048, kvh = c >> 7, d = c & 127;
#pragma unroll
      for (int mi = 0; mi < 4; ++mi)
#pragma unroll
        for (int r = 0; r < 4; ++r) {
          int grow = rbase + mi * 16 + r;
          int bb = grow >> 11, ss = grow & 2047;
          Ko[((size_t)(bb * NKV + kvh) * SEQ + ss) * HD + d] = f2bf(acc[mi][ni][r]);
        }
    } else {
      int c = gn - 2560, kvh = c >> 7, d = c & 127;
#pragma unroll
      for (int mi = 0; mi < 4; ++mi) {
        int grow0 = rbase + mi * 16;
        int bb = grow0 >> 11, ss = grow0 & 2047;
        s16x4 pk;
#pragma unroll
        for (int r = 0; r < 4; ++r) pk[r] = (short)f2bf(acc[mi][ni][r]);
        *(s16x4*)(Vo + ((size_t)(bb * NKV + kvh) * HD + d) * SEQ + ss) = pk;
      }
    }
  }
}

// ---------------- O-proj GEMM; XCD-swizzled grid ----------------
__global__ __launch_bounds__(256) void gemm_out(
    const unsigned short* __restrict__ A, const unsigned short* __restrict__ BT,
    float* __restrict__ C) {
  __shared__ __align__(16) unsigned short la[128][32];
  __shared__ __align__(16) unsigned short lb[128][32];
  int tid = threadIdx.x, lane = tid & 63, w = tid >> 6;
  int lin = blockIdx.x;
  int swz = (lin & 7) * 64 + (lin >> 3);
  int bx = swz % 16, by = swz / 16;
  int m0 = by * 128, n0 = bx * 128;
  int wr = (w >> 1) * 64, wc = (w & 1) * 64;
  int fr = lane & 15, kg = (lane >> 4) * 8, rg = (lane >> 4) * 4;
  f32x4 acc[4][4] = {};
  for (int kt = 0; kt < KDIM; kt += 32) {
    __syncthreads();
#pragma unroll
    for (int i = 0; i < 2; ++i) {
      int idx = tid + i * 256;
      int row = idx >> 2, seg = idx & 3;
      gload_lds16(A + (size_t)(m0 + row) * KDIM + kt + seg * 8,
                  (char*)la + (size_t)(i * 256 + w * 64) * 16);
      gload_lds16(BT + (size_t)(n0 + row) * KDIM + kt + seg * 8,
                  (char*)lb + (size_t)(i * 256 + w * 64) * 16);
    }
    __syncthreads();
    s16x8 af[4], bf[4];
#pragma unroll
    for (int mi = 0; mi < 4; ++mi) af[mi] = *(const s16x8*)(&la[wr + mi * 16 + fr][kg]);
#pragma unroll
    for (int ni = 0; ni < 4; ++ni) bf[ni] = *(const s16x8*)(&lb[wc + ni * 16 + fr][kg]);
#pragma unroll
    for (int mi = 0; mi < 4; ++mi)
#pragma unroll
      for (int ni = 0; ni < 4; ++ni) acc[mi][ni] = MFMA16(af[mi], bf[ni], acc[mi][ni]);
  }
  int rbase = m0 + wr + rg;
#pragma unroll
  for (int ni = 0; ni < 4; ++ni) {
    int gn = n0 + wc + ni * 16 + fr;
#pragma unroll
    for (int mi = 0; mi < 4; ++mi)
#pragma unroll
      for (int r = 0; r < 4; ++r)
        C[(size_t)(rbase + mi * 16 + r) * 2048 + gn] = acc[mi][ni][r];
  }
}

// ---------------- RoPE on [rows][128]; Q and K fused in one launch ----------------
__global__ __launch_bounds__(256) void rope2(
    unsigned short* __restrict__ Qx, unsigned short* __restrict__ Kx,
    const float* __restrict__ tbl) {
  __shared__ __align__(16) unsigned short xs[32][136];
  int tid = threadIdx.x;
  int bid = blockIdx.x;
  unsigned short* X;
  size_t r0;
  if (bid < 2048) { X = Qx; r0 = (size_t)bid * 32; }
  else            { X = Kx; r0 = (size_t)(bid - 2048) * 32; }
#pragma unroll
  for (int i = 0; i < 2; ++i) {
    int idx = tid + i * 256;
    int pr = idx >> 4, seg = idx & 15;
    *(s16x8*)(&xs[pr][seg * 8]) = *(const s16x8*)(X + (r0 + pr) * 128 + seg * 8);
  }
  __syncthreads();
  int pr = tid >> 3, jb = (tid & 7) * 8;
  size_t row = r0 + pr;
  int s = (int)(row & (SEQ - 1));
  s16x8 o0, o1;
#pragma unroll
  for (int j0 = 0; j0 < 8; ++j0) {
    int j = jb + j0;
    float c  = tbl[(s * 64 + j) * 2];
    float sn = tbl[(s * 64 + j) * 2 + 1];
    float xj   = bf2f(xs[pr][j]);
    float xj64 = bf2f(xs[pr][j + 64]);
    float x2j  = bf2f(xs[pr][2 * j]);
    float x2j1 = bf2f(xs[pr][2 * j + 1]);
    o0[j0] = (short)f2bf(xj * c - x2j1 * sn);
    o1[j0] = (short)f2bf(xj64 * c + x2j * sn);
  }
  unsigned short* xp = X + row * 128;
  *(s16x8*)(xp + jb)      = o0;
  *(s16x8*)(xp + 64 + jb) = o1;
}

// ---------------- Flash attention v13: 32x32 MFMA, per-lane q, in-register softmax ----------------
// grid 1024 x 128thr (2 waves x 32 q-rows = 64-row q-tile). XCD (l&7) owns one (b,kvh).
// slotq->qt mapping makes each CU's round-robin block set {x,x+8,x+16,x+24} uniform (66 rounds).
// Single-buffered K[64][136] + V^T[128][68] LDS (34.8KB), R6 2-barrier schedule,
// reg-staged async prefetch. S^T via mfma32(K,Q): lane owns q=lane&31; lane^32 holds
// complementary kv half -> softmax = in-lane tree + 1 shfl_xor(32); P->PV operand via
// cvt_pk_bf16 + permlane32_swap (no LDS round-trip, no broadcasts).
__global__ __launch_bounds__(128, 2) void attn_fwd(
    const unsigned short* __restrict__ Q, const unsigned short* __restrict__ K,
    const unsigned short* __restrict__ VT, const float* __restrict__ mask,
    unsigned short* __restrict__ O) {
  __shared__ __align__(16) unsigned short kt_[64][136];
  __shared__ __align__(16) unsigned short vt_[128][68];

  int tid = threadIdx.x, lane = tid & 63, w = tid >> 6;      // w 0..1
  int l = blockIdx.x;
  int grp = l & 7, slot = l >> 3;                            // slot 0..127
  int hloc = slot & 3;
  int sq = slot >> 2, g8 = sq >> 3, pos = sq & 7;            // balanced qt mapping
  int qt = (g8 == 0) ? 31 - pos : (g8 == 1) ? pos : (g8 == 2) ? 23 - pos : 8 + pos;
  int b = grp >> 2, kvh = grp & 3, h = kvh * 4 + hloc;
  int qbase = qt * 64;
  int qw = qbase + w * 32;                                   // wave's 32 q-rows
  int lq = lane & 31, hi = lane >> 5, hi8 = hi * 8;

  const unsigned short* Qb = Q + (size_t)(b * NH + h) * SEQ * HD;
  const unsigned short* Kb = K + (size_t)(b * NKV + kvh) * SEQ * HD;
  const unsigned short* Vb = VT + (size_t)(b * NKV + kvh) * HD * SEQ;
  const float* mb = mask + (size_t)b * SEQ;

  int krow = tid >> 4, kpos = (tid & 15) * 8;                // K rows krow+8i
  const float sc2 = 0.12751744584812722f;                    // 1/sqrt(128) * log2(e)
  const float L2E = 1.44269504088896f;
  int bS = b * SEQ;
  int ntiles = qt + 1;
  int q = qw + lq;                                           // lane's q row

  // Q fragments (B-operand of 32x32x16): lane holds Q[q][st*16 + hi*8 + j]
  s16x8 aq[8];
#pragma unroll
  for (int st = 0; st < 8; ++st)
    aq[st] = *(const s16x8*)(Qb + (size_t)q * HD + st * 16 + hi8);

  f32x16 oacc[4] = {};
  float m_r = -3e38f, l_r = 0.f;

  s16x8 kreg[8], vreg[8];
  // prologue: K(0) -> regs -> kt_; V(0) -> regs (written at top of round 0)
#pragma unroll
  for (int i = 0; i < 8; ++i)
    kreg[i] = *(const s16x8*)(Kb + (size_t)(krow + 8 * i) * HD + kpos);
#pragma unroll
  for (int i = 0; i < 8; ++i) {
    int c = tid + 128 * i;
    vreg[i] = *(const s16x8*)(Vb + (size_t)(c >> 3) * SEQ + (c & 7) * 8);
  }
#pragma unroll
  for (int i = 0; i < 8; ++i)
    *(s16x8*)(&kt_[krow + 8 * i][kpos]) = kreg[i];
  BARRIER_LDS();

  for (int t = 0; t < ntiles; ++t) {
    int kv0 = t * 64;
    bool notlast = (t + 1 < ntiles);
    bool diag = (t == qt);

    // write V(t) -> LDS; issue K(t+1) -> regs (latency hidden under QK^T+softmax)
#pragma unroll
    for (int i = 0; i < 8; ++i) {
      int c = tid + 128 * i;
      *(s16x8*)(&vt_[c >> 3][(c & 7) * 8]) = vreg[i];
    }
    if (notlast) {
#pragma unroll
      for (int i = 0; i < 8; ++i)
        kreg[i] = *(const s16x8*)(Kb + (size_t)(kv0 + 64 + krow + 8 * i) * HD + kpos);
    }

    // QK^T: S^T = K.Q^T, 2 kv-blocks of 32. D: col=lq(q), row=(r&3)+8*(r>>2)+4*hi
    f32x16 sA = {}, sB = {};
    __builtin_amdgcn_s_setprio(1);
#pragma unroll
    for (int st = 0; st < 8; ++st) {
      s16x8 ka = *(const s16x8*)(&kt_[lq][st * 16 + hi8]);
      s16x8 kb = *(const s16x8*)(&kt_[32 + lq][st * 16 + hi8]);
      sA = MFMA32(ka, aq[st], sA);
      sB = MFMA32(kb, aq[st], sB);
    }
    __builtin_amdgcn_s_setprio(0);

    // scale + mask (log2 domain); causal select only on diagonal tile
#pragma unroll
    for (int blk = 0; blk < 2; ++blk) {
#pragma unroll
      for (int rq = 0; rq < 4; ++rq) {
        float4 mv = *(const float4*)(mb + kv0 + blk * 32 + rq * 8 + 4 * hi);
        float mvr[4] = {mv.x * L2E, mv.y * L2E, mv.z * L2E, mv.w * L2E};
#pragma unroll
        for (int j = 0; j < 4; ++j) {
          int r = rq * 4 + j;
          float v = (blk ? sB[r] : sA[r]) * sc2 + mvr[j];
          if (diag) {
            int kv = kv0 + blk * 32 + rq * 8 + 4 * hi + j;
            v = (kv <= q) ? v : -3e38f;
          }
          if (blk) sB[r] = v; else sA[r] = v;
        }
      }
    }

    // online softmax (exp2 domain): in-lane tree + ONE shfl_xor(32); all per-lane after
    float pm = -3e38f;
#pragma unroll
    for (int r = 0; r < 16; ++r) pm = fmaxf(pm, fmaxf(sA[r], sB[r]));
    pm = fmaxf(pm, __shfl_xor(pm, 32, 64));
    if (!__all(pm - m_r <= 8.0f)) {
      float mn = fmaxf(m_r, pm);
      float al = exp2f(m_r - mn);
      m_r = mn;
      l_r *= al;
#pragma unroll
      for (int d4 = 0; d4 < 4; ++d4)
#pragma unroll
        for (int r = 0; r < 16; ++r) oacc[d4][r] *= al;
    }
    float rs = 0.f;
#pragma unroll
    for (int r = 0; r < 16; ++r) {
      float pa = exp2f(sA[r] - m_r), pb = exp2f(sB[r] - m_r);
      sA[r] = pa; sB[r] = pb;
      rs += pa + pb;
    }
    rs += __shfl_xor(rs, 32, 64);
    l_r += rs;

    // pack P -> B-operand frags via cvt_pk + permlane32_swap (one swap fills two words)
    s16x8 pf[4];
#pragma unroll
    for (int ks = 0; ks < 4; ++ks) {
      int a = (ks & 1) * 8;
      unsigned X0, X1, Y0, Y1;
      if (ks < 2) {
        X0 = cvtpk(sA[a + 0], sA[a + 1]); X1 = cvtpk(sA[a + 2], sA[a + 3]);
        Y0 = cvtpk(sA[a + 4], sA[a + 5]); Y1 = cvtpk(sA[a + 6], sA[a + 7]);
      } else {
        X0 = cvtpk(sB[a + 0], sB[a + 1]); X1 = cvtpk(sB[a + 2], sB[a + 3]);
        Y0 = cvtpk(sB[a + 4], sB[a + 5]); Y1 = cvtpk(sB[a + 6], sB[a + 7]);
      }
      pl32swap(X0, Y0);   // X0 -> w0, Y0 -> w2
      pl32swap(X1, Y1);   // X1 -> w1, Y1 -> w3
      union { unsigned u[4]; s16x8 v; } pk;
      pk.u[0] = X0; pk.u[1] = X1; pk.u[2] = Y0; pk.u[3] = Y1;
      pf[ks] = pk.v;
    }

    BARRIER_LDS();  // B1: kt_ reads done; vt_ = V(t) visible

    // write K(t+1) into kt_; issue V(t+1) -> regs (hidden under PV)
    if (notlast) {
#pragma unroll
      for (int i = 0; i < 8; ++i)
        *(s16x8*)(&kt_[krow + 8 * i][kpos]) = kreg[i];
#pragma unroll
      for (int i = 0; i < 8; ++i) {
        int c = tid + 128 * i;
        vreg[i] = *(const s16x8*)(Vb + (size_t)(c >> 3) * SEQ + kv0 + 64 + (c & 7) * 8);
      }
    }

    // PV: O^T += V^T . P ; A = V^T frag (row=d, k=kv), B = pf[ks]
    __builtin_amdgcn_s_setprio(1);
#pragma unroll
    for (int d4 = 0; d4 < 4; ++d4) {
#pragma unroll
      for (int ks = 0; ks < 4; ++ks) {
        s16x8 vf = *(const s16x8*)(&vt_[d4 * 32 + lq][ks * 16 + hi8]);
        oacc[d4] = MFMA32(vf, pf[ks], oacc[d4]);
      }
    }
    __builtin_amdgcn_s_setprio(0);

    BARRIER_LDS();  // B2: kt_ = K(t+1) visible; vt_ reads done
  }

  // epilogue: O[q][d], d = d4*32 + rq*8 + 4*hi + j ; per-lane normalize
  float iv = 1.0f / l_r;
  unsigned short* orow = O + (size_t)(bS + q) * 2048 + h * 128;
#pragma unroll
  for (int d4 = 0; d4 < 4; ++d4) {
#pragma unroll
    for (int rq = 0; rq < 4; ++rq) {
      s16x4 pk;
#pragma unroll
      for (int j = 0; j < 4; ++j) pk[j] = (short)f2bf(oacc[d4][rq * 4 + j] * iv);
      *(s16x4*)(orow + d4 * 32 + rq * 8 + 4 * hi) = pk;
    }
  }
}

extern "C" void kernel_launch(void* const* d_in, const int* in_sizes, int n_in,
                              void* d_out, int out_size, void* d_ws, size_t ws_size,
                              hipStream_t stream) {
  const float* hidden = (const float*)d_in[0];
  const float* mask   = (const float*)d_in[1];
  const float* Wq     = (const float*)d_in[2];
  const float* Wk     = (const float*)d_in[3];
  const float* Wv     = (const float*)d_in[4];
  const float* Wo     = (const float*)d_in[5];
  float* out = (float*)d_out;

  char* ws = (char*)d_ws;
  unsigned short* BT  = (unsigned short*)(ws);                 // 3072x2048 bf16
  unsigned short* WoT = (unsigned short*)(ws + 12582912);      // 2048x2048 bf16
  unsigned short* Qb  = (unsigned short*)(ws + 20971520);      // [B][NH][S][HD]
  unsigned short* Kb  = (unsigned short*)(ws + 37748736);      // [B][NKV][S][HD]
  unsigned short* VT  = (unsigned short*)(ws + 41943040);      // [B][NKV][HD][S]
  unsigned short* AO  = (unsigned short*)(ws + 46137344);      // [MROWS][2048] bf16
  float*          tbl = (float*)(ws + 62914560);               // [S][64][2] f32
  unsigned short* Ab  = AO;  // hidden as bf16; dead before attn writes AO

  conv_bf16<<<MROWS * KDIM / (256 * 8), 256, 0, stream>>>(hidden, Ab);
  prep_weights<<<dim3(160, 64), 256, 0, stream>>>(Wq, Wk, Wv, Wo, BT, WoT);
  rope_table_kernel<<<512, 256, 0, stream>>>(tbl);

  gemm_qkv<<<dim3(768), 256, 0, stream>>>(Ab, BT, Qb, Kb, VT);
  rope2<<<dim3(2048 + 512), 256, 0, stream>>>(Qb, Kb, tbl);
  attn_fwd<<<dim3(1024), 128, 0, stream>>>(Qb, Kb, VT, mask, AO);
  gemm_out<<<dim3(512), 256, 0, stream>>>(AO, WoT, out);
}

// Round 14
// 222.970 us; speedup vs baseline: 1.0980x; 1.0980x over previous
//
#include <hip/hip_runtime.h>
#include <hip/hip_bf16.h>

#define BATCH 2
#define SEQ   2048
#define NH    16
#define NKV   4
#define HD    128
#define KDIM  2048
#define MROWS 4096
#define NQKV  3072

typedef __attribute__((ext_vector_type(8))) short  s16x8;
typedef __attribute__((ext_vector_type(4))) short  s16x4;
typedef __attribute__((ext_vector_type(4))) float  f32x4;
typedef __attribute__((ext_vector_type(8))) __bf16 b16x8;

// barrier that drains LDS ops only -- leaves global prefetch loads in flight
#define BARRIER_LDS() do { \
    asm volatile("s_waitcnt lgkmcnt(0)" ::: "memory"); \
    __builtin_amdgcn_s_barrier(); \
  } while (0)

__device__ __forceinline__ unsigned short f2bf(float f) {
  __hip_bfloat16 h = __float2bfloat16(f);
  return *reinterpret_cast<unsigned short*>(&h);
}
__device__ __forceinline__ float bf2f(unsigned short h) {
  union { unsigned int u; float f; } x; x.u = ((unsigned int)h) << 16;
  return x.f;
}

__device__ __forceinline__ f32x4 MFMA16(s16x8 a, s16x8 b, f32x4 c) {
  return __builtin_amdgcn_mfma_f32_16x16x32_bf16(
      __builtin_bit_cast(b16x8, a), __builtin_bit_cast(b16x8, b), c, 0, 0, 0);
}

__device__ __forceinline__ void gload_lds16(const void* g, void* lds) {
  __builtin_amdgcn_global_load_lds(
      (const __attribute__((address_space(1))) void*)g,
      (__attribute__((address_space(3))) void*)lds, 16, 0, 0);
}

// ---------------- fused weight prep: all 4 transposes in one launch ----------------
__global__ __launch_bounds__(256) void prep_weights(
    const float* __restrict__ Wq, const float* __restrict__ Wk,
    const float* __restrict__ Wv, const float* __restrict__ Wo,
    unsigned short* __restrict__ BT, unsigned short* __restrict__ WoT) {
  __shared__ float tile[32][33];
  int bx = blockIdx.x;
  const float* W; unsigned short* WT; int Nd, nb;
  if (bx < 64)       { W = Wq; WT = BT;                          Nd = 2048; nb = bx; }
  else if (bx < 80)  { W = Wk; WT = BT + (size_t)2048 * KDIM;    Nd = 512;  nb = bx - 64; }
  else if (bx < 96)  { W = Wv; WT = BT + (size_t)2560 * KDIM;    Nd = 512;  nb = bx - 80; }
  else               { W = Wo; WT = WoT;                         Nd = 2048; nb = bx - 96; }
  int n0 = nb * 32, k0 = blockIdx.y * 32;
  int tx = threadIdx.x & 31, ty = threadIdx.x >> 5;
#pragma unroll
  for (int i = 0; i < 4; ++i)
    tile[ty + i * 8][tx] = W[(size_t)(k0 + ty + i * 8) * Nd + n0 + tx];
  __syncthreads();
#pragma unroll
  for (int i = 0; i < 4; ++i)
    WT[(size_t)(n0 + ty + i * 8) * KDIM + k0 + tx] = f2bf(tile[tx][ty + i * 8]);
}

// ---------------- f32 -> bf16 bulk convert ----------------
__global__ __launch_bounds__(256) void conv_bf16(
    const float* __restrict__ X, unsigned short* __restrict__ Y) {
  int i = blockIdx.x * 256 + threadIdx.x;
  const float4 a = ((const float4*)X)[2 * i];
  const float4 b = ((const float4*)X)[2 * i + 1];
  s16x8 o;
  o[0] = (short)f2bf(a.x); o[1] = (short)f2bf(a.y);
  o[2] = (short)f2bf(a.z); o[3] = (short)f2bf(a.w);
  o[4] = (short)f2bf(b.x); o[5] = (short)f2bf(b.y);
  o[6] = (short)f2bf(b.z); o[7] = (short)f2bf(b.w);
  ((s16x8*)Y)[i] = o;
}

// ---------------- RoPE cos/sin table ----------------
__global__ __launch_bounds__(256) void rope_table_kernel(float* __restrict__ tbl) {
  int i = blockIdx.x * 256 + threadIdx.x;
  int s = i >> 6, j = i & 63;
  float inv = powf(10000.0f, -(float)(2 * j) * (1.0f / 128.0f));
  float f = (float)s * inv;
  tbl[2 * i]     = cosf(f);
  tbl[2 * i + 1] = sinf(f);
}

// ---------------- QKV GEMM v2: 256x256 tile, BK=32, 4-deep LDS ring, counted vmcnt ----------------
// 512 thr = 8 waves (wm 0..1, wn 0..3); per-wave 128x64 output (8x4 frags).
// Ring: K-tile kt lives in buf kt&3; staged during group kt-2; at group kt entry
// vmcnt(4) retires kt's 4 loads (kt+1's 4 stay in flight) + one barrier.
// Swizzle: LDS chunk (r,c) holds global chunk (r, c^(r&3)); reads invert it.
__global__ __launch_bounds__(512, 2) void gemm_qkv(
    const unsigned short* __restrict__ A, const unsigned short* __restrict__ BT,
    unsigned short* __restrict__ Qo, unsigned short* __restrict__ Ko,
    unsigned short* __restrict__ Vo) {
  __shared__ __align__(16) unsigned short lds[4][2][8192];   // [ring][A,B][256*32]
  int tid = threadIdx.x, lane = tid & 63;
  int w = tid >> 6, wm = w >> 2, wn = w & 3;
  int lin = blockIdx.x;
  int swz = (lin & 7) * 24 + (lin >> 3);                     // 192 = 8 XCD x 24
  int bx = swz % 12, by = swz / 12;
  int m0 = by * 256, n0 = bx * 256;
  int fr = lane & 15, cg4 = lane >> 4, rg4 = (lane >> 4) * 4;

  // staging: thread t covers 16B chunks t and t+512 of each 16KB tile
  int rS1 = tid >> 2,        cS1 = (tid & 3) ^ (rS1 & 3);
  int t2  = tid + 512;
  int rS2 = t2 >> 2,         cS2 = (t2 & 3) ^ (rS2 & 3);

  f32x4 acc[8][4] = {};

  // prologue: stage K-tiles 0 and 1 (A then B each; 8 loads total per thread... 4 pairs)
#pragma unroll
  for (int kt = 0; kt < 2; ++kt) {
    gload_lds16(A + (size_t)(m0 + rS1) * KDIM + kt * 32 + cS1 * 8,
                (char*)&lds[kt][0][0] + (size_t)tid * 16);
    gload_lds16(A + (size_t)(m0 + rS2) * KDIM + kt * 32 + cS2 * 8,
                (char*)&lds[kt][0][0] + (size_t)t2 * 16);
    gload_lds16(BT + (size_t)(n0 + rS1) * KDIM + kt * 32 + cS1 * 8,
                (char*)&lds[kt][1][0] + (size_t)tid * 16);
    gload_lds16(BT + (size_t)(n0 + rS2) * KDIM + kt * 32 + cS2 * 8,
                (char*)&lds[kt][1][0] + (size_t)t2 * 16);
  }

  for (int kt = 0; kt < KDIM / 32; ++kt) {
    int buf = kt & 3;
    asm volatile("s_waitcnt vmcnt(4)" ::: "memory");  // kt's 4 loads landed; kt+1's in flight
    __builtin_amdgcn_s_barrier();

    const unsigned short* lA = &lds[buf][0][0];
    const unsigned short* lB = &lds[buf][1][0];
    s16x8 bfr[4], afr[4];
#pragma unroll
    for (int nf = 0; nf < 4; ++nf) {
      int rb = wn * 64 + nf * 16 + fr;
      bfr[nf] = *(const s16x8*)(lB + rb * 32 + (cg4 ^ (rb & 3)) * 8);
    }
#pragma unroll
    for (int mf = 0; mf < 4; ++mf) {
      int ra = wm * 128 + mf * 16 + fr;
      afr[mf] = *(const s16x8*)(lA + ra * 32 + (cg4 ^ (ra & 3)) * 8);
    }
    if (kt + 2 < KDIM / 32) {   // stage A(kt+2) into ring buf (kt+2)&3
      int nb = (kt + 2) & 3, ko = (kt + 2) * 32;
      gload_lds16(A + (size_t)(m0 + rS1) * KDIM + ko + cS1 * 8,
                  (char*)&lds[nb][0][0] + (size_t)tid * 16);
      gload_lds16(A + (size_t)(m0 + rS2) * KDIM + ko + cS2 * 8,
                  (char*)&lds[nb][0][0] + (size_t)t2 * 16);
    }
    __builtin_amdgcn_s_setprio(1);
#pragma unroll
    for (int mf = 0; mf < 4; ++mf)
#pragma unroll
      for (int nf = 0; nf < 4; ++nf)
        acc[mf][nf] = MFMA16(afr[mf], bfr[nf], acc[mf][nf]);
    __builtin_amdgcn_s_setprio(0);
#pragma unroll
    for (int mf = 0; mf < 4; ++mf) {
      int ra = wm * 128 + (mf + 4) * 16 + fr;
      afr[mf] = *(const s16x8*)(lA + ra * 32 + (cg4 ^ (ra & 3)) * 8);
    }
    if (kt + 2 < KDIM / 32) {   // stage B(kt+2)
      int nb = (kt + 2) & 3, ko = (kt + 2) * 32;
      gload_lds16(BT + (size_t)(n0 + rS1) * KDIM + ko + cS1 * 8,
                  (char*)&lds[nb][1][0] + (size_t)tid * 16);
      gload_lds16(BT + (size_t)(n0 + rS2) * KDIM + ko + cS2 * 8,
                  (char*)&lds[nb][1][0] + (size_t)t2 * 16);
    }
    __builtin_amdgcn_s_setprio(1);
#pragma unroll
    for (int mf = 0; mf < 4; ++mf)
#pragma unroll
      for (int nf = 0; nf < 4; ++nf)
        acc[mf + 4][nf] = MFMA16(afr[mf], bfr[nf], acc[mf + 4][nf]);
    __builtin_amdgcn_s_setprio(0);
  }

  // epilogue scatter: Q [B][NH][S][HD], K [B][NKV][S][HD], V^T [B][NKV][HD][S]
  int rbase = m0 + wm * 128 + rg4;
#pragma unroll
  for (int nf = 0; nf < 4; ++nf) {
    int gn = n0 + wn * 64 + nf * 16 + fr;
    if (gn < 2048) {
      int hh = gn >> 7, d = gn & 127;
#pragma unroll
      for (int mf = 0; mf < 8; ++mf)
#pragma unroll
        for (int r = 0; r < 4; ++r) {
          int grow = rbase + mf * 16 + r;
          int bb = grow >> 11, ss = grow & 2047;
          Qo[((size_t)(bb * NH + hh) * SEQ + ss) * HD + d] = f2bf(acc[mf][nf][r]);
        }
    } else if (gn < 2560) {
      int c = gn - 2048, kvh = c >> 7, d = c & 127;
#pragma unroll
      for (int mf = 0; mf < 8; ++mf)
#pragma unroll
        for (int r = 0; r < 4; ++r) {
          int grow = rbase + mf * 16 + r;
          int bb = grow >> 11, ss = grow & 2047;
          Ko[((size_t)(bb * NKV + kvh) * SEQ + ss) * HD + d] = f2bf(acc[mf][nf][r]);
        }
    } else {
      int c = gn - 2560, kvh = c >> 7, d = c & 127;
#pragma unroll
      for (int mf = 0; mf < 8; ++mf) {
        int grow0 = rbase + mf * 16;
        int bb = grow0 >> 11, ss = grow0 & 2047;
        s16x4 pk;
#pragma unroll
        for (int r = 0; r < 4; ++r) pk[r] = (short)f2bf(acc[mf][nf][r]);
        *(s16x4*)(Vo + ((size_t)(bb * NKV + kvh) * HD + d) * SEQ + ss) = pk;
      }
    }
  }
}

// ---------------- O-proj GEMM; XCD-swizzled grid ----------------
__global__ __launch_bounds__(256) void gemm_out(
    const unsigned short* __restrict__ A, const unsigned short* __restrict__ BT,
    float* __restrict__ C) {
  __shared__ __align__(16) unsigned short la[128][32];
  __shared__ __align__(16) unsigned short lb[128][32];
  int tid = threadIdx.x, lane = tid & 63, w = tid >> 6;
  int lin = blockIdx.x;
  int swz = (lin & 7) * 64 + (lin >> 3);
  int bx = swz % 16, by = swz / 16;
  int m0 = by * 128, n0 = bx * 128;
  int wr = (w >> 1) * 64, wc = (w & 1) * 64;
  int fr = lane & 15, kg = (lane >> 4) * 8, rg = (lane >> 4) * 4;
  f32x4 acc[4][4] = {};
  for (int kt = 0; kt < KDIM; kt += 32) {
    __syncthreads();
#pragma unroll
    for (int i = 0; i < 2; ++i) {
      int idx = tid + i * 256;
      int row = idx >> 2, seg = idx & 3;
      gload_lds16(A + (size_t)(m0 + row) * KDIM + kt + seg * 8,
                  (char*)la + (size_t)(i * 256 + w * 64) * 16);
      gload_lds16(BT + (size_t)(n0 + row) * KDIM + kt + seg * 8,
                  (char*)lb + (size_t)(i * 256 + w * 64) * 16);
    }
    __syncthreads();
    s16x8 af[4], bf[4];
#pragma unroll
    for (int mi = 0; mi < 4; ++mi) af[mi] = *(const s16x8*)(&la[wr + mi * 16 + fr][kg]);
#pragma unroll
    for (int ni = 0; ni < 4; ++ni) bf[ni] = *(const s16x8*)(&lb[wc + ni * 16 + fr][kg]);
#pragma unroll
    for (int mi = 0; mi < 4; ++mi)
#pragma unroll
      for (int ni = 0; ni < 4; ++ni) acc[mi][ni] = MFMA16(af[mi], bf[ni], acc[mi][ni]);
  }
  int rbase = m0 + wr + rg;
#pragma unroll
  for (int ni = 0; ni < 4; ++ni) {
    int gn = n0 + wc + ni * 16 + fr;
#pragma unroll
    for (int mi = 0; mi < 4; ++mi)
#pragma unroll
      for (int r = 0; r < 4; ++r)
        C[(size_t)(rbase + mi * 16 + r) * 2048 + gn] = acc[mi][ni][r];
  }
}

// ---------------- RoPE on [rows][128]; Q and K fused in one launch ----------------
__global__ __launch_bounds__(256) void rope2(
    unsigned short* __restrict__ Qx, unsigned short* __restrict__ Kx,
    const float* __restrict__ tbl) {
  __shared__ __align__(16) unsigned short xs[32][136];
  int tid = threadIdx.x;
  int bid = blockIdx.x;
  unsigned short* X;
  size_t r0;
  if (bid < 2048) { X = Qx; r0 = (size_t)bid * 32; }
  else            { X = Kx; r0 = (size_t)(bid - 2048) * 32; }
#pragma unroll
  for (int i = 0; i < 2; ++i) {
    int idx = tid + i * 256;
    int pr = idx >> 4, seg = idx & 15;
    *(s16x8*)(&xs[pr][seg * 8]) = *(const s16x8*)(X + (r0 + pr) * 128 + seg * 8);
  }
  __syncthreads();
  int pr = tid >> 3, jb = (tid & 7) * 8;
  size_t row = r0 + pr;
  int s = (int)(row & (SEQ - 1));
  s16x8 o0, o1;
#pragma unroll
  for (int j0 = 0; j0 < 8; ++j0) {
    int j = jb + j0;
    float c  = tbl[(s * 64 + j) * 2];
    float sn = tbl[(s * 64 + j) * 2 + 1];
    float xj   = bf2f(xs[pr][j]);
    float xj64 = bf2f(xs[pr][j + 64]);
    float x2j  = bf2f(xs[pr][2 * j]);
    float x2j1 = bf2f(xs[pr][2 * j + 1]);
    o0[j0] = (short)f2bf(xj * c - x2j1 * sn);
    o1[j0] = (short)f2bf(xj64 * c + x2j * sn);
  }
  unsigned short* xp = X + row * 128;
  *(s16x8*)(xp + jb)      = o0;
  *(s16x8*)(xp + 64 + jb) = o1;
}

// ---------------- Flash attention v12: K+V double-buffered, ONE barrier/tile ----------------
__global__ __launch_bounds__(256, 2) void attn_fwd(
    const unsigned short* __restrict__ Q, const unsigned short* __restrict__ K,
    const unsigned short* __restrict__ VT, const float* __restrict__ mask,
    unsigned short* __restrict__ O) {
  __shared__ __align__(16) unsigned short kt_[2][64][136];
  __shared__ __align__(16) unsigned short vt_[2][128][68];
  __shared__ __align__(16) unsigned short pt_[4][16][36];

  int tid = threadIdx.x, lane = tid & 63, w = tid >> 6;
  int l = blockIdx.x;
  int grp = l & 7, slot = l >> 3;
  int hloc = slot & 3, qt = 31 - (slot >> 2);    // big q-tiles dispatch first
  int b = grp >> 2, kvh = grp & 3, h = kvh * 4 + hloc;
  int qbase = qt * 64;
  int qw = qbase + w * 16;                       // wave's 16 q-rows
  int fr = lane & 15, g = lane >> 4, kg = g * 8, rg = g * 4;

  const unsigned short* Qb = Q + (size_t)(b * NH + h) * SEQ * HD;
  const unsigned short* Kb = K + (size_t)(b * NKV + kvh) * SEQ * HD;
  const unsigned short* Vb = VT + (size_t)(b * NKV + kvh) * HD * SEQ;
  const float* mb = mask + (size_t)b * SEQ;

  int krow = tid >> 4, kpos = (tid & 15) * 8;
  const float sc2 = 0.12751744584812722f;        // 1/sqrt(128) * log2(e)
  const float L2E = 1.44269504088896f;
  int bS = b * SEQ;
  int ntiles = qt + 1;

  s16x8 aq[4];
#pragma unroll
  for (int dc = 0; dc < 4; ++dc)
    aq[dc] = *(const s16x8*)(Qb + (size_t)(qw + fr) * HD + dc * 32 + kg);

  f32x4 oacc[8] = {};
  float m_r = -3e38f, l_r = 0.f;

  s16x8 kreg[4], vreg[4];
#pragma unroll
  for (int i = 0; i < 4; ++i)
    kreg[i] = *(const s16x8*)(Kb + (size_t)(krow + i * 16) * HD + kpos);
#pragma unroll
  for (int i = 0; i < 4; ++i) {
    int c = tid + 256 * i;
    vreg[i] = *(const s16x8*)(Vb + (size_t)(c >> 3) * SEQ + (c & 7) * 8);
  }
#pragma unroll
  for (int i = 0; i < 4; ++i)
    *(s16x8*)(&kt_[0][krow + i * 16][kpos]) = kreg[i];
#pragma unroll
  for (int i = 0; i < 4; ++i) {
    int c = tid + 256 * i;
    *(s16x8*)(&vt_[0][c >> 3][(c & 7) * 8]) = vreg[i];
  }
  if (ntiles > 1) {
#pragma unroll
    for (int i = 0; i < 4; ++i)
      kreg[i] = *(const s16x8*)(Kb + (size_t)(64 + krow + i * 16) * HD + kpos);
#pragma unroll
    for (int i = 0; i < 4; ++i) {
      int c = tid + 256 * i;
      vreg[i] = *(const s16x8*)(Vb + (size_t)(c >> 3) * SEQ + 64 + (c & 7) * 8);
    }
  }
  BARRIER_LDS();

  for (int t = 0; t < ntiles; ++t) {
    int kv0 = t * 64;
    int cur = t & 1;
    bool diag = (t == qt);

    if (t + 1 < ntiles) {
#pragma unroll
      for (int i = 0; i < 4; ++i)
        *(s16x8*)(&kt_[cur ^ 1][krow + i * 16][kpos]) = kreg[i];
#pragma unroll
      for (int i = 0; i < 4; ++i) {
        int c = tid + 256 * i;
        *(s16x8*)(&vt_[cur ^ 1][c >> 3][(c & 7) * 8]) = vreg[i];
      }
      if (t + 2 < ntiles) {
#pragma unroll
        for (int i = 0; i < 4; ++i)
          kreg[i] = *(const s16x8*)(Kb + (size_t)(kv0 + 128 + krow + i * 16) * HD + kpos);
#pragma unroll
        for (int i = 0; i < 4; ++i) {
          int c = tid + 256 * i;
          vreg[i] = *(const s16x8*)(Vb + (size_t)(c >> 3) * SEQ + kv0 + 128 + (c & 7) * 8);
        }
      }
    }

    f32x4 sf[4];
    __builtin_amdgcn_s_setprio(1);
#pragma unroll
    for (int mk = 0; mk < 4; ++mk) {
      s16x8 ak[4];
#pragma unroll
      for (int dc = 0; dc < 4; ++dc)
        ak[dc] = *(const s16x8*)(&kt_[cur][mk * 16 + fr][dc * 32 + kg]);
      sf[mk] = f32x4{0.f, 0.f, 0.f, 0.f};
#pragma unroll
      for (int dc = 0; dc < 4; ++dc)
        sf[mk] = MFMA16(ak[dc], aq[dc], sf[mk]);
    }
    __builtin_amdgcn_s_setprio(0);

#pragma unroll
    for (int mk = 0; mk < 4; ++mk) {
      float4 mv = *(const float4*)(mb + kv0 + mk * 16 + rg);
      float mvr[4] = {mv.x * L2E, mv.y * L2E, mv.z * L2E, mv.w * L2E};
      if (diag) {
#pragma unroll
        for (int r = 0; r < 4; ++r) {
          int kv = kv0 + mk * 16 + rg + r;
          float v = sf[mk][r] * sc2 + mvr[r];
          sf[mk][r] = (kv <= qw + fr) ? v : -3e38f;
        }
      } else {
#pragma unroll
        for (int r = 0; r < 4; ++r)
          sf[mk][r] = sf[mk][r] * sc2 + mvr[r];
      }
    }

    float pm01a = fmaxf(sf[0][0], sf[0][1]), pm01b = fmaxf(sf[0][2], sf[0][3]);
    float pm11a = fmaxf(sf[1][0], sf[1][1]), pm11b = fmaxf(sf[1][2], sf[1][3]);
    float pm21a = fmaxf(sf[2][0], sf[2][1]), pm21b = fmaxf(sf[2][2], sf[2][3]);
    float pm31a = fmaxf(sf[3][0], sf[3][1]), pm31b = fmaxf(sf[3][2], sf[3][3]);
    float pm0 = fmaxf(pm01a, pm01b), pm1 = fmaxf(pm11a, pm11b);
    float pm2 = fmaxf(pm21a, pm21b), pm3 = fmaxf(pm31a, pm31b);
    float pm = fmaxf(fmaxf(pm0, pm1), fmaxf(pm2, pm3));
    pm = fmaxf(pm, __shfl_xor(pm, 16, 64));
    pm = fmaxf(pm, __shfl_xor(pm, 32, 64));
    if (!__all(pm - m_r <= 8.0f)) {
      float mo = m_r;
      float mn = fmaxf(mo, pm);
      float al = exp2f(mo - mn);
      m_r = mn;
      l_r *= al;
#pragma unroll
      for (int r = 0; r < 4; ++r) {
        float ar = __shfl(al, rg + r, 16);
#pragma unroll
        for (int od = 0; od < 8; ++od) oacc[od][r] *= ar;
      }
    }
    float rs = 0.f;
#pragma unroll
    for (int mk = 0; mk < 4; ++mk)
#pragma unroll
      for (int r = 0; r < 4; ++r) {
        float ppv = exp2f(sf[mk][r] - m_r);
        sf[mk][r] = ppv;
        rs += ppv;
      }
    rs += __shfl_xor(rs, 16, 64);
    rs += __shfl_xor(rs, 32, 64);
    l_r += rs;

#pragma unroll
    for (int kk = 0; kk < 2; ++kk) {
#pragma unroll
      for (int mh = 0; mh < 2; ++mh) {
        int mk = kk * 2 + mh;
        s16x4 pk;
#pragma unroll
        for (int r = 0; r < 4; ++r) pk[r] = (short)f2bf(sf[mk][r]);
        *(s16x4*)(&pt_[w][fr][mh * 16 + rg]) = pk;
      }
      s16x8 ap = *(const s16x8*)(&pt_[w][fr][kg]);
      __builtin_amdgcn_s_setprio(1);
#pragma unroll
      for (int od = 0; od < 8; ++od) {
        s16x8 bv = *(const s16x8*)(&vt_[cur][od * 16 + fr][kk * 32 + kg]);
        oacc[od] = MFMA16(ap, bv, oacc[od]);
      }
      __builtin_amdgcn_s_setprio(0);
    }

    BARRIER_LDS();
  }

  float iv = 1.0f / l_r;
  float ivr[4];
#pragma unroll
  for (int r = 0; r < 4; ++r) ivr[r] = __shfl(iv, rg + r, 16);
#pragma unroll
  for (int r = 0; r < 4; ++r) {
    unsigned short* op = O + (size_t)(bS + qw + rg + r) * 2048 + h * 128 + fr;
#pragma unroll
    for (int od = 0; od < 8; ++od)
      op[od * 16] = f2bf(oacc[od][r] * ivr[r]);
  }
}

extern "C" void kernel_launch(void* const* d_in, const int* in_sizes, int n_in,
                              void* d_out, int out_size, void* d_ws, size_t ws_size,
                              hipStream_t stream) {
  const float* hidden = (const float*)d_in[0];
  const float* mask   = (const float*)d_in[1];
  const float* Wq     = (const float*)d_in[2];
  const float* Wk     = (const float*)d_in[3];
  const float* Wv     = (const float*)d_in[4];
  const float* Wo     = (const float*)d_in[5];
  float* out = (float*)d_out;

  char* ws = (char*)d_ws;
  unsigned short* BT  = (unsigned short*)(ws);                 // 3072x2048 bf16
  unsigned short* WoT = (unsigned short*)(ws + 12582912);      // 2048x2048 bf16
  unsigned short* Qb  = (unsigned short*)(ws + 20971520);      // [B][NH][S][HD]
  unsigned short* Kb  = (unsigned short*)(ws + 37748736);      // [B][NKV][S][HD]
  unsigned short* VT  = (unsigned short*)(ws + 41943040);      // [B][NKV][HD][S]
  unsigned short* AO  = (unsigned short*)(ws + 46137344);      // [MROWS][2048] bf16
  float*          tbl = (float*)(ws + 62914560);               // [S][64][2] f32
  unsigned short* Ab  = AO;  // hidden as bf16; dead before attn writes AO

  conv_bf16<<<MROWS * KDIM / (256 * 8), 256, 0, stream>>>(hidden, Ab);
  prep_weights<<<dim3(160, 64), 256, 0, stream>>>(Wq, Wk, Wv, Wo, BT, WoT);
  rope_table_kernel<<<512, 256, 0, stream>>>(tbl);

  gemm_qkv<<<dim3(192), 512, 0, stream>>>(Ab, BT, Qb, Kb, VT);
  rope2<<<dim3(2048 + 512), 256, 0, stream>>>(Qb, Kb, tbl);
  attn_fwd<<<dim3(1024), 256, 0, stream>>>(Qb, Kb, VT, mask, AO);
  gemm_out<<<dim3(512), 256, 0, stream>>>(AO, WoT, out);
}

// Round 15
// 220.467 us; speedup vs baseline: 1.1105x; 1.0114x over previous
//
#include <hip/hip_runtime.h>
#include <hip/hip_bf16.h>

#define BATCH 2
#define SEQ   2048
#define NH    16
#define NKV   4
#define HD    128
#define KDIM  2048
#define MROWS 4096
#define NQKV  3072

typedef __attribute__((ext_vector_type(8))) short  s16x8;
typedef __attribute__((ext_vector_type(4))) short  s16x4;
typedef __attribute__((ext_vector_type(4))) float  f32x4;
typedef __attribute__((ext_vector_type(8))) __bf16 b16x8;

// barrier that drains LDS ops only -- leaves global prefetch loads in flight
#define BARRIER_LDS() do { \
    asm volatile("s_waitcnt lgkmcnt(0)" ::: "memory"); \
    __builtin_amdgcn_s_barrier(); \
  } while (0)

__device__ __forceinline__ unsigned short f2bf(float f) {
  __hip_bfloat16 h = __float2bfloat16(f);
  return *reinterpret_cast<unsigned short*>(&h);
}
__device__ __forceinline__ float bf2f(unsigned short h) {
  union { unsigned int u; float f; } x; x.u = ((unsigned int)h) << 16;
  return x.f;
}

__device__ __forceinline__ f32x4 MFMA16(s16x8 a, s16x8 b, f32x4 c) {
  return __builtin_amdgcn_mfma_f32_16x16x32_bf16(
      __builtin_bit_cast(b16x8, a), __builtin_bit_cast(b16x8, b), c, 0, 0, 0);
}

__device__ __forceinline__ void gload_lds16(const void* g, void* lds) {
  __builtin_amdgcn_global_load_lds(
      (const __attribute__((address_space(1))) void*)g,
      (__attribute__((address_space(3))) void*)lds, 16, 0, 0);
}

// ---------------- fused weight prep: all 4 transposes in one launch ----------------
__global__ __launch_bounds__(256) void prep_weights(
    const float* __restrict__ Wq, const float* __restrict__ Wk,
    const float* __restrict__ Wv, const float* __restrict__ Wo,
    unsigned short* __restrict__ BT, unsigned short* __restrict__ WoT) {
  __shared__ float tile[32][33];
  int bx = blockIdx.x;
  const float* W; unsigned short* WT; int Nd, nb;
  if (bx < 64)       { W = Wq; WT = BT;                          Nd = 2048; nb = bx; }
  else if (bx < 80)  { W = Wk; WT = BT + (size_t)2048 * KDIM;    Nd = 512;  nb = bx - 64; }
  else if (bx < 96)  { W = Wv; WT = BT + (size_t)2560 * KDIM;    Nd = 512;  nb = bx - 80; }
  else               { W = Wo; WT = WoT;                         Nd = 2048; nb = bx - 96; }
  int n0 = nb * 32, k0 = blockIdx.y * 32;
  int tx = threadIdx.x & 31, ty = threadIdx.x >> 5;
#pragma unroll
  for (int i = 0; i < 4; ++i)
    tile[ty + i * 8][tx] = W[(size_t)(k0 + ty + i * 8) * Nd + n0 + tx];
  __syncthreads();
#pragma unroll
  for (int i = 0; i < 4; ++i)
    WT[(size_t)(n0 + ty + i * 8) * KDIM + k0 + tx] = f2bf(tile[tx][ty + i * 8]);
}

// ---------------- f32 -> bf16 bulk convert ----------------
__global__ __launch_bounds__(256) void conv_bf16(
    const float* __restrict__ X, unsigned short* __restrict__ Y) {
  int i = blockIdx.x * 256 + threadIdx.x;
  const float4 a = ((const float4*)X)[2 * i];
  const float4 b = ((const float4*)X)[2 * i + 1];
  s16x8 o;
  o[0] = (short)f2bf(a.x); o[1] = (short)f2bf(a.y);
  o[2] = (short)f2bf(a.z); o[3] = (short)f2bf(a.w);
  o[4] = (short)f2bf(b.x); o[5] = (short)f2bf(b.y);
  o[6] = (short)f2bf(b.z); o[7] = (short)f2bf(b.w);
  ((s16x8*)Y)[i] = o;
}

// ---------------- RoPE cos/sin table ----------------
__global__ __launch_bounds__(256) void rope_table_kernel(float* __restrict__ tbl) {
  int i = blockIdx.x * 256 + threadIdx.x;
  int s = i >> 6, j = i & 63;
  float inv = powf(10000.0f, -(float)(2 * j) * (1.0f / 128.0f));
  float f = (float)s * inv;
  tbl[2 * i]     = cosf(f);
  tbl[2 * i + 1] = sinf(f);
}

// ---------------- QKV GEMM v2: 256x256 tile, BK=32, 4-deep LDS ring, counted vmcnt ----------------
__global__ __launch_bounds__(512, 2) void gemm_qkv(
    const unsigned short* __restrict__ A, const unsigned short* __restrict__ BT,
    unsigned short* __restrict__ Qo, unsigned short* __restrict__ Ko,
    unsigned short* __restrict__ Vo) {
  __shared__ __align__(16) unsigned short lds[4][2][8192];   // [ring][A,B][256*32]
  int tid = threadIdx.x, lane = tid & 63;
  int w = tid >> 6, wm = w >> 2, wn = w & 3;
  int lin = blockIdx.x;
  int swz = (lin & 7) * 24 + (lin >> 3);                     // 192 = 8 XCD x 24
  int bx = swz % 12, by = swz / 12;
  int m0 = by * 256, n0 = bx * 256;
  int fr = lane & 15, cg4 = lane >> 4, rg4 = (lane >> 4) * 4;

  int rS1 = tid >> 2,        cS1 = (tid & 3) ^ (rS1 & 3);
  int t2  = tid + 512;
  int rS2 = t2 >> 2,         cS2 = (t2 & 3) ^ (rS2 & 3);

  f32x4 acc[8][4] = {};

#pragma unroll
  for (int kt = 0; kt < 2; ++kt) {
    gload_lds16(A + (size_t)(m0 + rS1) * KDIM + kt * 32 + cS1 * 8,
                (char*)&lds[kt][0][0] + (size_t)tid * 16);
    gload_lds16(A + (size_t)(m0 + rS2) * KDIM + kt * 32 + cS2 * 8,
                (char*)&lds[kt][0][0] + (size_t)t2 * 16);
    gload_lds16(BT + (size_t)(n0 + rS1) * KDIM + kt * 32 + cS1 * 8,
                (char*)&lds[kt][1][0] + (size_t)tid * 16);
    gload_lds16(BT + (size_t)(n0 + rS2) * KDIM + kt * 32 + cS2 * 8,
                (char*)&lds[kt][1][0] + (size_t)t2 * 16);
  }

  for (int kt = 0; kt < KDIM / 32; ++kt) {
    int buf = kt & 3;
    asm volatile("s_waitcnt vmcnt(4)" ::: "memory");
    __builtin_amdgcn_s_barrier();

    const unsigned short* lA = &lds[buf][0][0];
    const unsigned short* lB = &lds[buf][1][0];
    s16x8 bfr[4], afr[4];
#pragma unroll
    for (int nf = 0; nf < 4; ++nf) {
      int rb = wn * 64 + nf * 16 + fr;
      bfr[nf] = *(const s16x8*)(lB + rb * 32 + (cg4 ^ (rb & 3)) * 8);
    }
#pragma unroll
    for (int mf = 0; mf < 4; ++mf) {
      int ra = wm * 128 + mf * 16 + fr;
      afr[mf] = *(const s16x8*)(lA + ra * 32 + (cg4 ^ (ra & 3)) * 8);
    }
    if (kt + 2 < KDIM / 32) {
      int nb = (kt + 2) & 3, ko = (kt + 2) * 32;
      gload_lds16(A + (size_t)(m0 + rS1) * KDIM + ko + cS1 * 8,
                  (char*)&lds[nb][0][0] + (size_t)tid * 16);
      gload_lds16(A + (size_t)(m0 + rS2) * KDIM + ko + cS2 * 8,
                  (char*)&lds[nb][0][0] + (size_t)t2 * 16);
    }
    __builtin_amdgcn_s_setprio(1);
#pragma unroll
    for (int mf = 0; mf < 4; ++mf)
#pragma unroll
      for (int nf = 0; nf < 4; ++nf)
        acc[mf][nf] = MFMA16(afr[mf], bfr[nf], acc[mf][nf]);
    __builtin_amdgcn_s_setprio(0);
#pragma unroll
    for (int mf = 0; mf < 4; ++mf) {
      int ra = wm * 128 + (mf + 4) * 16 + fr;
      afr[mf] = *(const s16x8*)(lA + ra * 32 + (cg4 ^ (ra & 3)) * 8);
    }
    if (kt + 2 < KDIM / 32) {
      int nb = (kt + 2) & 3, ko = (kt + 2) * 32;
      gload_lds16(BT + (size_t)(n0 + rS1) * KDIM + ko + cS1 * 8,
                  (char*)&lds[nb][1][0] + (size_t)tid * 16);
      gload_lds16(BT + (size_t)(n0 + rS2) * KDIM + ko + cS2 * 8,
                  (char*)&lds[nb][1][0] + (size_t)t2 * 16);
    }
    __builtin_amdgcn_s_setprio(1);
#pragma unroll
    for (int mf = 0; mf < 4; ++mf)
#pragma unroll
      for (int nf = 0; nf < 4; ++nf)
        acc[mf + 4][nf] = MFMA16(afr[mf], bfr[nf], acc[mf + 4][nf]);
    __builtin_amdgcn_s_setprio(0);
  }

  int rbase = m0 + wm * 128 + rg4;
#pragma unroll
  for (int nf = 0; nf < 4; ++nf) {
    int gn = n0 + wn * 64 + nf * 16 + fr;
    if (gn < 2048) {
      int hh = gn >> 7, d = gn & 127;
#pragma unroll
      for (int mf = 0; mf < 8; ++mf)
#pragma unroll
        for (int r = 0; r < 4; ++r) {
          int grow = rbase + mf * 16 + r;
          int bb = grow >> 11, ss = grow & 2047;
          Qo[((size_t)(bb * NH + hh) * SEQ + ss) * HD + d] = f2bf(acc[mf][nf][r]);
        }
    } else if (gn < 2560) {
      int c = gn - 2048, kvh = c >> 7, d = c & 127;
#pragma unroll
      for (int mf = 0; mf < 8; ++mf)
#pragma unroll
        for (int r = 0; r < 4; ++r) {
          int grow = rbase + mf * 16 + r;
          int bb = grow >> 11, ss = grow & 2047;
          Ko[((size_t)(bb * NKV + kvh) * SEQ + ss) * HD + d] = f2bf(acc[mf][nf][r]);
        }
    } else {
      int c = gn - 2560, kvh = c >> 7, d = c & 127;
#pragma unroll
      for (int mf = 0; mf < 8; ++mf) {
        int grow0 = rbase + mf * 16;
        int bb = grow0 >> 11, ss = grow0 & 2047;
        s16x4 pk;
#pragma unroll
        for (int r = 0; r < 4; ++r) pk[r] = (short)f2bf(acc[mf][nf][r]);
        *(s16x4*)(Vo + ((size_t)(bb * NKV + kvh) * HD + d) * SEQ + ss) = pk;
      }
    }
  }
}

// ---------------- O-proj GEMM v2: 256x128 tile, BK=32, 4-deep ring, counted vmcnt ----------------
// 512 thr = 8 waves (wm 0..1 over 128 rows, wn 0..3 over 32 cols); acc 8x2.
// 256 blocks = 1/CU. Per thread per K-tile: A 2 chunks + B 1 chunk -> vmcnt(3).
__global__ __launch_bounds__(512, 1) void gemm_out(
    const unsigned short* __restrict__ A, const unsigned short* __restrict__ BT,
    float* __restrict__ C) {
  __shared__ __align__(16) unsigned short ldsA[4][8192];     // 256x32
  __shared__ __align__(16) unsigned short ldsB[4][4096];     // 128x32
  int tid = threadIdx.x, lane = tid & 63;
  int w = tid >> 6, wm = w >> 2, wn = w & 3;
  int lin = blockIdx.x;
  int swz = (lin & 7) * 32 + (lin >> 3);                     // 256 = 8 XCD x 32
  int bx = swz % 16, by = swz / 16;
  int m0 = by * 256, n0 = bx * 128;
  int fr = lane & 15, cg4 = lane >> 4, rg4 = (lane >> 4) * 4;

  int rS1 = tid >> 2,  cS1 = (tid & 3) ^ (rS1 & 3);          // A chunk 1
  int t2  = tid + 512;
  int rS2 = t2 >> 2,   cS2 = (t2 & 3) ^ (rS2 & 3);           // A chunk 2
  int rB  = tid >> 2,  cB  = (tid & 3) ^ (rB & 3);           // B chunk (rB<128)
  bool doB = (tid < 512);  // all threads stage B? B has 512 chunks -> 1 per thread
  // B tile: 128 rows x 4 chunks = 512 chunks; thread t -> chunk t (rB = t>>2 < 128) ✓

  f32x4 acc[8][2] = {};

#pragma unroll
  for (int kt = 0; kt < 2; ++kt) {
    gload_lds16(A + (size_t)(m0 + rS1) * KDIM + kt * 32 + cS1 * 8,
                (char*)&ldsA[kt][0] + (size_t)tid * 16);
    gload_lds16(A + (size_t)(m0 + rS2) * KDIM + kt * 32 + cS2 * 8,
                (char*)&ldsA[kt][0] + (size_t)t2 * 16);
    gload_lds16(BT + (size_t)(n0 + rB) * KDIM + kt * 32 + cB * 8,
                (char*)&ldsB[kt][0] + (size_t)tid * 16);
  }

  for (int kt = 0; kt < KDIM / 32; ++kt) {
    int buf = kt & 3;
    asm volatile("s_waitcnt vmcnt(3)" ::: "memory");  // kt's 3 landed; kt+1's in flight
    __builtin_amdgcn_s_barrier();

    const unsigned short* lA = &ldsA[buf][0];
    const unsigned short* lB = &ldsB[buf][0];
    s16x8 bfr[2], afr[4];
#pragma unroll
    for (int nf = 0; nf < 2; ++nf) {
      int rb = wn * 32 + nf * 16 + fr;
      bfr[nf] = *(const s16x8*)(lB + rb * 32 + (cg4 ^ (rb & 3)) * 8);
    }
#pragma unroll
    for (int mf = 0; mf < 4; ++mf) {
      int ra = wm * 128 + mf * 16 + fr;
      afr[mf] = *(const s16x8*)(lA + ra * 32 + (cg4 ^ (ra & 3)) * 8);
    }
    if (kt + 2 < KDIM / 32) {   // stage A(kt+2)
      int nb = (kt + 2) & 3, ko = (kt + 2) * 32;
      gload_lds16(A + (size_t)(m0 + rS1) * KDIM + ko + cS1 * 8,
                  (char*)&ldsA[nb][0] + (size_t)tid * 16);
      gload_lds16(A + (size_t)(m0 + rS2) * KDIM + ko + cS2 * 8,
                  (char*)&ldsA[nb][0] + (size_t)t2 * 16);
    }
    __builtin_amdgcn_s_setprio(1);
#pragma unroll
    for (int mf = 0; mf < 4; ++mf)
#pragma unroll
      for (int nf = 0; nf < 2; ++nf)
        acc[mf][nf] = MFMA16(afr[mf], bfr[nf], acc[mf][nf]);
    __builtin_amdgcn_s_setprio(0);
#pragma unroll
    for (int mf = 0; mf < 4; ++mf) {
      int ra = wm * 128 + (mf + 4) * 16 + fr;
      afr[mf] = *(const s16x8*)(lA + ra * 32 + (cg4 ^ (ra & 3)) * 8);
    }
    if (kt + 2 < KDIM / 32) {   // stage B(kt+2)
      int nb = (kt + 2) & 3, ko = (kt + 2) * 32;
      gload_lds16(BT + (size_t)(n0 + rB) * KDIM + ko + cB * 8,
                  (char*)&ldsB[nb][0] + (size_t)tid * 16);
    }
    __builtin_amdgcn_s_setprio(1);
#pragma unroll
    for (int mf = 0; mf < 4; ++mf)
#pragma unroll
      for (int nf = 0; nf < 2; ++nf)
        acc[mf + 4][nf] = MFMA16(afr[mf], bfr[nf], acc[mf + 4][nf]);
    __builtin_amdgcn_s_setprio(0);
  }

  int rbase = m0 + wm * 128 + rg4;
#pragma unroll
  for (int nf = 0; nf < 2; ++nf) {
    int gn = n0 + wn * 32 + nf * 16 + fr;
#pragma unroll
    for (int mf = 0; mf < 8; ++mf)
#pragma unroll
      for (int r = 0; r < 4; ++r)
        C[(size_t)(rbase + mf * 16 + r) * 2048 + gn] = acc[mf][nf][r];
  }
}

// ---------------- RoPE on [rows][128]; Q and K fused in one launch ----------------
__global__ __launch_bounds__(256) void rope2(
    unsigned short* __restrict__ Qx, unsigned short* __restrict__ Kx,
    const float* __restrict__ tbl) {
  __shared__ __align__(16) unsigned short xs[32][136];
  int tid = threadIdx.x;
  int bid = blockIdx.x;
  unsigned short* X;
  size_t r0;
  if (bid < 2048) { X = Qx; r0 = (size_t)bid * 32; }
  else            { X = Kx; r0 = (size_t)(bid - 2048) * 32; }
#pragma unroll
  for (int i = 0; i < 2; ++i) {
    int idx = tid + i * 256;
    int pr = idx >> 4, seg = idx & 15;
    *(s16x8*)(&xs[pr][seg * 8]) = *(const s16x8*)(X + (r0 + pr) * 128 + seg * 8);
  }
  __syncthreads();
  int pr = tid >> 3, jb = (tid & 7) * 8;
  size_t row = r0 + pr;
  int s = (int)(row & (SEQ - 1));
  s16x8 o0, o1;
#pragma unroll
  for (int j0 = 0; j0 < 8; ++j0) {
    int j = jb + j0;
    float c  = tbl[(s * 64 + j) * 2];
    float sn = tbl[(s * 64 + j) * 2 + 1];
    float xj   = bf2f(xs[pr][j]);
    float xj64 = bf2f(xs[pr][j + 64]);
    float x2j  = bf2f(xs[pr][2 * j]);
    float x2j1 = bf2f(xs[pr][2 * j + 1]);
    o0[j0] = (short)f2bf(xj * c - x2j1 * sn);
    o1[j0] = (short)f2bf(xj64 * c + x2j * sn);
  }
  unsigned short* xp = X + row * 128;
  *(s16x8*)(xp + jb)      = o0;
  *(s16x8*)(xp + 64 + jb) = o1;
}

// ---------------- Flash attention v12: K+V double-buffered, ONE barrier/tile ----------------
__global__ __launch_bounds__(256, 2) void attn_fwd(
    const unsigned short* __restrict__ Q, const unsigned short* __restrict__ K,
    const unsigned short* __restrict__ VT, const float* __restrict__ mask,
    unsigned short* __restrict__ O) {
  __shared__ __align__(16) unsigned short kt_[2][64][136];
  __shared__ __align__(16) unsigned short vt_[2][128][68];
  __shared__ __align__(16) unsigned short pt_[4][16][36];

  int tid = threadIdx.x, lane = tid & 63, w = tid >> 6;
  int l = blockIdx.x;
  int grp = l & 7, slot = l >> 3;
  int hloc = slot & 3, qt = 31 - (slot >> 2);
  int b = grp >> 2, kvh = grp & 3, h = kvh * 4 + hloc;
  int qbase = qt * 64;
  int qw = qbase + w * 16;
  int fr = lane & 15, g = lane >> 4, kg = g * 8, rg = g * 4;

  const unsigned short* Qb = Q + (size_t)(b * NH + h) * SEQ * HD;
  const unsigned short* Kb = K + (size_t)(b * NKV + kvh) * SEQ * HD;
  const unsigned short* Vb = VT + (size_t)(b * NKV + kvh) * HD * SEQ;
  const float* mb = mask + (size_t)b * SEQ;

  int krow = tid >> 4, kpos = (tid & 15) * 8;
  const float sc2 = 0.12751744584812722f;
  const float L2E = 1.44269504088896f;
  int bS = b * SEQ;
  int ntiles = qt + 1;

  s16x8 aq[4];
#pragma unroll
  for (int dc = 0; dc < 4; ++dc)
    aq[dc] = *(const s16x8*)(Qb + (size_t)(qw + fr) * HD + dc * 32 + kg);

  f32x4 oacc[8] = {};
  float m_r = -3e38f, l_r = 0.f;

  s16x8 kreg[4], vreg[4];
#pragma unroll
  for (int i = 0; i < 4; ++i)
    kreg[i] = *(const s16x8*)(Kb + (size_t)(krow + i * 16) * HD + kpos);
#pragma unroll
  for (int i = 0; i < 4; ++i) {
    int c = tid + 256 * i;
    vreg[i] = *(const s16x8*)(Vb + (size_t)(c >> 3) * SEQ + (c & 7) * 8);
  }
#pragma unroll
  for (int i = 0; i < 4; ++i)
    *(s16x8*)(&kt_[0][krow + i * 16][kpos]) = kreg[i];
#pragma unroll
  for (int i = 0; i < 4; ++i) {
    int c = tid + 256 * i;
    *(s16x8*)(&vt_[0][c >> 3][(c & 7) * 8]) = vreg[i];
  }
  if (ntiles > 1) {
#pragma unroll
    for (int i = 0; i < 4; ++i)
      kreg[i] = *(const s16x8*)(Kb + (size_t)(64 + krow + i * 16) * HD + kpos);
#pragma unroll
    for (int i = 0; i < 4; ++i) {
      int c = tid + 256 * i;
      vreg[i] = *(const s16x8*)(Vb + (size_t)(c >> 3) * SEQ + 64 + (c & 7) * 8);
    }
  }
  BARRIER_LDS();

  for (int t = 0; t < ntiles; ++t) {
    int kv0 = t * 64;
    int cur = t & 1;
    bool diag = (t == qt);

    if (t + 1 < ntiles) {
#pragma unroll
      for (int i = 0; i < 4; ++i)
        *(s16x8*)(&kt_[cur ^ 1][krow + i * 16][kpos]) = kreg[i];
#pragma unroll
      for (int i = 0; i < 4; ++i) {
        int c = tid + 256 * i;
        *(s16x8*)(&vt_[cur ^ 1][c >> 3][(c & 7) * 8]) = vreg[i];
      }
      if (t + 2 < ntiles) {
#pragma unroll
        for (int i = 0; i < 4; ++i)
          kreg[i] = *(const s16x8*)(Kb + (size_t)(kv0 + 128 + krow + i * 16) * HD + kpos);
#pragma unroll
        for (int i = 0; i < 4; ++i) {
          int c = tid + 256 * i;
          vreg[i] = *(const s16x8*)(Vb + (size_t)(c >> 3) * SEQ + kv0 + 128 + (c & 7) * 8);
        }
      }
    }

    f32x4 sf[4];
    __builtin_amdgcn_s_setprio(1);
#pragma unroll
    for (int mk = 0; mk < 4; ++mk) {
      s16x8 ak[4];
#pragma unroll
      for (int dc = 0; dc < 4; ++dc)
        ak[dc] = *(const s16x8*)(&kt_[cur][mk * 16 + fr][dc * 32 + kg]);
      sf[mk] = f32x4{0.f, 0.f, 0.f, 0.f};
#pragma unroll
      for (int dc = 0; dc < 4; ++dc)
        sf[mk] = MFMA16(ak[dc], aq[dc], sf[mk]);
    }
    __builtin_amdgcn_s_setprio(0);

#pragma unroll
    for (int mk = 0; mk < 4; ++mk) {
      float4 mv = *(const float4*)(mb + kv0 + mk * 16 + rg);
      float mvr[4] = {mv.x * L2E, mv.y * L2E, mv.z * L2E, mv.w * L2E};
      if (diag) {
#pragma unroll
        for (int r = 0; r < 4; ++r) {
          int kv = kv0 + mk * 16 + rg + r;
          float v = sf[mk][r] * sc2 + mvr[r];
          sf[mk][r] = (kv <= qw + fr) ? v : -3e38f;
        }
      } else {
#pragma unroll
        for (int r = 0; r < 4; ++r)
          sf[mk][r] = sf[mk][r] * sc2 + mvr[r];
      }
    }

    float pm01a = fmaxf(sf[0][0], sf[0][1]), pm01b = fmaxf(sf[0][2], sf[0][3]);
    float pm11a = fmaxf(sf[1][0], sf[1][1]), pm11b = fmaxf(sf[1][2], sf[1][3]);
    float pm21a = fmaxf(sf[2][0], sf[2][1]), pm21b = fmaxf(sf[2][2], sf[2][3]);
    float pm31a = fmaxf(sf[3][0], sf[3][1]), pm31b = fmaxf(sf[3][2], sf[3][3]);
    float pm0 = fmaxf(pm01a, pm01b), pm1 = fmaxf(pm11a, pm11b);
    float pm2 = fmaxf(pm21a, pm21b), pm3 = fmaxf(pm31a, pm31b);
    float pm = fmaxf(fmaxf(pm0, pm1), fmaxf(pm2, pm3));
    pm = fmaxf(pm, __shfl_xor(pm, 16, 64));
    pm = fmaxf(pm, __shfl_xor(pm, 32, 64));
    if (!__all(pm - m_r <= 8.0f)) {
      float mo = m_r;
      float mn = fmaxf(mo, pm);
      float al = exp2f(mo - mn);
      m_r = mn;
      l_r *= al;
#pragma unroll
      for (int r = 0; r < 4; ++r) {
        float ar = __shfl(al, rg + r, 16);
#pragma unroll
        for (int od = 0; od < 8; ++od) oacc[od][r] *= ar;
      }
    }
    float rs = 0.f;
#pragma unroll
    for (int mk = 0; mk < 4; ++mk)
#pragma unroll
      for (int r = 0; r < 4; ++r) {
        float ppv = exp2f(sf[mk][r] - m_r);
        sf[mk][r] = ppv;
        rs += ppv;
      }
    rs += __shfl_xor(rs, 16, 64);
    rs += __shfl_xor(rs, 32, 64);
    l_r += rs;

#pragma unroll
    for (int kk = 0; kk < 2; ++kk) {
#pragma unroll
      for (int mh = 0; mh < 2; ++mh) {
        int mk = kk * 2 + mh;
        s16x4 pk;
#pragma unroll
        for (int r = 0; r < 4; ++r) pk[r] = (short)f2bf(sf[mk][r]);
        *(s16x4*)(&pt_[w][fr][mh * 16 + rg]) = pk;
      }
      s16x8 ap = *(const s16x8*)(&pt_[w][fr][kg]);
      __builtin_amdgcn_s_setprio(1);
#pragma unroll
      for (int od = 0; od < 8; ++od) {
        s16x8 bv = *(const s16x8*)(&vt_[cur][od * 16 + fr][kk * 32 + kg]);
        oacc[od] = MFMA16(ap, bv, oacc[od]);
      }
      __builtin_amdgcn_s_setprio(0);
    }

    BARRIER_LDS();
  }

  float iv = 1.0f / l_r;
  float ivr[4];
#pragma unroll
  for (int r = 0; r < 4; ++r) ivr[r] = __shfl(iv, rg + r, 16);
#pragma unroll
  for (int r = 0; r < 4; ++r) {
    unsigned short* op = O + (size_t)(bS + qw + rg + r) * 2048 + h * 128 + fr;
#pragma unroll
    for (int od = 0; od < 8; ++od)
      op[od * 16] = f2bf(oacc[od][r] * ivr[r]);
  }
}

extern "C" void kernel_launch(void* const* d_in, const int* in_sizes, int n_in,
                              void* d_out, int out_size, void* d_ws, size_t ws_size,
                              hipStream_t stream) {
  const float* hidden = (const float*)d_in[0];
  const float* mask   = (const float*)d_in[1];
  const float* Wq     = (const float*)d_in[2];
  const float* Wk     = (const float*)d_in[3];
  const float* Wv     = (const float*)d_in[4];
  const float* Wo     = (const float*)d_in[5];
  float* out = (float*)d_out;

  char* ws = (char*)d_ws;
  unsigned short* BT  = (unsigned short*)(ws);                 // 3072x2048 bf16
  unsigned short* WoT = (unsigned short*)(ws + 12582912);      // 2048x2048 bf16
  unsigned short* Qb  = (unsigned short*)(ws + 20971520);      // [B][NH][S][HD]
  unsigned short* Kb  = (unsigned short*)(ws + 37748736);      // [B][NKV][S][HD]
  unsigned short* VT  = (unsigned short*)(ws + 41943040);      // [B][NKV][HD][S]
  unsigned short* AO  = (unsigned short*)(ws + 46137344);      // [MROWS][2048] bf16
  float*          tbl = (float*)(ws + 62914560);               // [S][64][2] f32
  unsigned short* Ab  = AO;  // hidden as bf16; dead before attn writes AO

  conv_bf16<<<MROWS * KDIM / (256 * 8), 256, 0, stream>>>(hidden, Ab);
  prep_weights<<<dim3(160, 64), 256, 0, stream>>>(Wq, Wk, Wv, Wo, BT, WoT);
  rope_table_kernel<<<512, 256, 0, stream>>>(tbl);

  gemm_qkv<<<dim3(192), 512, 0, stream>>>(Ab, BT, Qb, Kb, VT);
  rope2<<<dim3(2048 + 512), 256, 0, stream>>>(Qb, Kb, tbl);
  attn_fwd<<<dim3(1024), 256, 0, stream>>>(Qb, Kb, VT, mask, AO);
  gemm_out<<<dim3(256), 512, 0, stream>>>(AO, WoT, out);
}

// Round 16
// 204.160 us; speedup vs baseline: 1.1992x; 1.0799x over previous
//
#include <hip/hip_runtime.h>
#include <hip/hip_bf16.h>

#define BATCH 2
#define SEQ   2048
#define NH    16
#define NKV   4
#define HD    128
#define KDIM  2048
#define MROWS 4096
#define NQKV  3072

typedef __attribute__((ext_vector_type(8))) short  s16x8;
typedef __attribute__((ext_vector_type(4))) short  s16x4;
typedef __attribute__((ext_vector_type(4))) float  f32x4;
typedef __attribute__((ext_vector_type(8))) __bf16 b16x8;

// barrier that drains LDS ops only -- leaves global prefetch loads in flight
#define BARRIER_LDS() do { \
    asm volatile("s_waitcnt lgkmcnt(0)" ::: "memory"); \
    __builtin_amdgcn_s_barrier(); \
  } while (0)

__device__ __forceinline__ unsigned short f2bf(float f) {
  __hip_bfloat16 h = __float2bfloat16(f);
  return *reinterpret_cast<unsigned short*>(&h);
}
__device__ __forceinline__ float bf2f(unsigned short h) {
  union { unsigned int u; float f; } x; x.u = ((unsigned int)h) << 16;
  return x.f;
}

__device__ __forceinline__ f32x4 MFMA16(s16x8 a, s16x8 b, f32x4 c) {
  return __builtin_amdgcn_mfma_f32_16x16x32_bf16(
      __builtin_bit_cast(b16x8, a), __builtin_bit_cast(b16x8, b), c, 0, 0, 0);
}

__device__ __forceinline__ void gload_lds16(const void* g, void* lds) {
  __builtin_amdgcn_global_load_lds(
      (const __attribute__((address_space(1))) void*)g,
      (__attribute__((address_space(3))) void*)lds, 16, 0, 0);
}

// ---------------- fused prep: hidden->bf16 + 4 weight transposes + rope table ----------------
// regions on blockIdx.x: [0,10240) weights (sub=bid%160, ky=bid/160);
// [10240,14336) conv; [14336,14848) rope table.
__global__ __launch_bounds__(256) void prep_all(
    const float* __restrict__ hidden,
    const float* __restrict__ Wq, const float* __restrict__ Wk,
    const float* __restrict__ Wv, const float* __restrict__ Wo,
    unsigned short* __restrict__ Ab, unsigned short* __restrict__ BT,
    unsigned short* __restrict__ WoT, float* __restrict__ tbl) {
  __shared__ float tile[32][33];
  int bid = blockIdx.x;
  if (bid < 10240) {
    int sub = bid % 160, ky = bid / 160;
    const float* W; unsigned short* WT; int Nd, nb;
    if (sub < 64)       { W = Wq; WT = BT;                       Nd = 2048; nb = sub; }
    else if (sub < 80)  { W = Wk; WT = BT + (size_t)2048 * KDIM; Nd = 512;  nb = sub - 64; }
    else if (sub < 96)  { W = Wv; WT = BT + (size_t)2560 * KDIM; Nd = 512;  nb = sub - 80; }
    else                { W = Wo; WT = WoT;                      Nd = 2048; nb = sub - 96; }
    int n0 = nb * 32, k0 = ky * 32;
    int tx = threadIdx.x & 31, ty = threadIdx.x >> 5;
#pragma unroll
    for (int i = 0; i < 4; ++i)
      tile[ty + i * 8][tx] = W[(size_t)(k0 + ty + i * 8) * Nd + n0 + tx];
    __syncthreads();
#pragma unroll
    for (int i = 0; i < 4; ++i)
      WT[(size_t)(n0 + ty + i * 8) * KDIM + k0 + tx] = f2bf(tile[tx][ty + i * 8]);
  } else if (bid < 14336) {
    int i = (bid - 10240) * 256 + threadIdx.x;
    const float4 a = ((const float4*)hidden)[2 * i];
    const float4 b = ((const float4*)hidden)[2 * i + 1];
    s16x8 o;
    o[0] = (short)f2bf(a.x); o[1] = (short)f2bf(a.y);
    o[2] = (short)f2bf(a.z); o[3] = (short)f2bf(a.w);
    o[4] = (short)f2bf(b.x); o[5] = (short)f2bf(b.y);
    o[6] = (short)f2bf(b.z); o[7] = (short)f2bf(b.w);
    ((s16x8*)Ab)[i] = o;
  } else {
    int i = (bid - 14336) * 256 + threadIdx.x;
    int s = i >> 6, j = i & 63;
    float inv = powf(10000.0f, -(float)(2 * j) * (1.0f / 128.0f));
    float f = (float)s * inv;
    tbl[2 * i]     = cosf(f);
    tbl[2 * i + 1] = sinf(f);
  }
}

// ---------------- QKV GEMM v3: 256x256, BK=32, 4-deep ring, counted vmcnt, fused RoPE ----------------
// Q/K-region blocks: acc -> LDS scratch (ring aliased, 256x260 bf16) -> rope -> per-head store.
// V-region blocks: direct transposed store. Block col-range is entirely one region.
__global__ __launch_bounds__(512, 2) void gemm_qkv(
    const unsigned short* __restrict__ A, const unsigned short* __restrict__ BT,
    const float* __restrict__ tbl,
    unsigned short* __restrict__ Qo, unsigned short* __restrict__ Ko,
    unsigned short* __restrict__ Vo) {
  __shared__ __align__(16) unsigned short lds_[66560];   // ring 4x2x8192 = 65536; scratch 256x260
#define RING(buf, ab) (lds_ + (((buf) * 2 + (ab)) << 13))
  int tid = threadIdx.x, lane = tid & 63;
  int w = tid >> 6, wm = w >> 2, wn = w & 3;
  int lin = blockIdx.x;
  int swz = (lin & 7) * 24 + (lin >> 3);                 // 192 = 8 XCD x 24
  int bx = swz % 12, by = swz / 12;
  int m0 = by * 256, n0 = bx * 256;
  int fr = lane & 15, cg4 = lane >> 4, rg4 = (lane >> 4) * 4;

  int rS1 = tid >> 2,        cS1 = (tid & 3) ^ (rS1 & 3);
  int t2  = tid + 512;
  int rS2 = t2 >> 2,         cS2 = (t2 & 3) ^ (rS2 & 3);

  f32x4 acc[8][4] = {};

#pragma unroll
  for (int kt = 0; kt < 2; ++kt) {
    gload_lds16(A + (size_t)(m0 + rS1) * KDIM + kt * 32 + cS1 * 8,
                (char*)RING(kt, 0) + (size_t)tid * 16);
    gload_lds16(A + (size_t)(m0 + rS2) * KDIM + kt * 32 + cS2 * 8,
                (char*)RING(kt, 0) + (size_t)t2 * 16);
    gload_lds16(BT + (size_t)(n0 + rS1) * KDIM + kt * 32 + cS1 * 8,
                (char*)RING(kt, 1) + (size_t)tid * 16);
    gload_lds16(BT + (size_t)(n0 + rS2) * KDIM + kt * 32 + cS2 * 8,
                (char*)RING(kt, 1) + (size_t)t2 * 16);
  }

  const int NK = KDIM / 32;
  for (int kt = 0; kt < NK; ++kt) {
    int buf = kt & 3;
    if (kt == NK - 1) asm volatile("s_waitcnt vmcnt(0)" ::: "memory");
    else              asm volatile("s_waitcnt vmcnt(4)" ::: "memory");
    __builtin_amdgcn_s_barrier();

    const unsigned short* lA = RING(buf, 0);
    const unsigned short* lB = RING(buf, 1);
    s16x8 bfr[4], afr[4];
#pragma unroll
    for (int nf = 0; nf < 4; ++nf) {
      int rb = wn * 64 + nf * 16 + fr;
      bfr[nf] = *(const s16x8*)(lB + rb * 32 + (cg4 ^ (rb & 3)) * 8);
    }
#pragma unroll
    for (int mf = 0; mf < 4; ++mf) {
      int ra = wm * 128 + mf * 16 + fr;
      afr[mf] = *(const s16x8*)(lA + ra * 32 + (cg4 ^ (ra & 3)) * 8);
    }
    if (kt + 2 < NK) {
      int nb = (kt + 2) & 3, ko = (kt + 2) * 32;
      gload_lds16(A + (size_t)(m0 + rS1) * KDIM + ko + cS1 * 8,
                  (char*)RING(nb, 0) + (size_t)tid * 16);
      gload_lds16(A + (size_t)(m0 + rS2) * KDIM + ko + cS2 * 8,
                  (char*)RING(nb, 0) + (size_t)t2 * 16);
    }
    __builtin_amdgcn_s_setprio(1);
#pragma unroll
    for (int mf = 0; mf < 4; ++mf)
#pragma unroll
      for (int nf = 0; nf < 4; ++nf)
        acc[mf][nf] = MFMA16(afr[mf], bfr[nf], acc[mf][nf]);
    __builtin_amdgcn_s_setprio(0);
#pragma unroll
    for (int mf = 0; mf < 4; ++mf) {
      int ra = wm * 128 + (mf + 4) * 16 + fr;
      afr[mf] = *(const s16x8*)(lA + ra * 32 + (cg4 ^ (ra & 3)) * 8);
    }
    if (kt + 2 < NK) {
      int nb = (kt + 2) & 3, ko = (kt + 2) * 32;
      gload_lds16(BT + (size_t)(n0 + rS1) * KDIM + ko + cS1 * 8,
                  (char*)RING(nb, 1) + (size_t)tid * 16);
      gload_lds16(BT + (size_t)(n0 + rS2) * KDIM + ko + cS2 * 8,
                  (char*)RING(nb, 1) + (size_t)t2 * 16);
    }
    __builtin_amdgcn_s_setprio(1);
#pragma unroll
    for (int mf = 0; mf < 4; ++mf)
#pragma unroll
      for (int nf = 0; nf < 4; ++nf)
        acc[mf + 4][nf] = MFMA16(afr[mf], bfr[nf], acc[mf + 4][nf]);
    __builtin_amdgcn_s_setprio(0);
  }

  if (bx < 10) {
    // ---- Q/K region: dump acc -> scratch, barrier, rope+store ----
    BARRIER_LDS();   // ring reads done across waves; safe to alias
    unsigned short* sc_ = lds_;          // 256 rows x 260 (padded) bf16
#pragma unroll
    for (int mf = 0; mf < 8; ++mf)
#pragma unroll
      for (int nf = 0; nf < 4; ++nf)
#pragma unroll
        for (int r = 0; r < 4; ++r)
          sc_[(wm * 128 + mf * 16 + rg4 + r) * 260 + wn * 64 + nf * 16 + fr] =
              f2bf(acc[mf][nf][r]);
    BARRIER_LDS();

    // 8 tasks/thread: task = (row 0..255, head-half 0..1, j-octet 0..7)
#pragma unroll
    for (int i = 0; i < 8; ++i) {
      int t = tid + 512 * i;
      int row = t >> 4, rem = t & 15;
      int hl = rem >> 3, j0 = (rem & 7) * 8;
      int grow = m0 + row, bb = grow >> 11, ss = grow & 2047;
      const unsigned short* xb = sc_ + row * 260 + hl * 128;
      s16x8 xj  = *(const s16x8*)(xb + j0);
      s16x8 xj6 = *(const s16x8*)(xb + 64 + j0);
      s16x8 x2a = *(const s16x8*)(xb + 2 * j0);
      s16x8 x2b = *(const s16x8*)(xb + 2 * j0 + 8);
      const float* tb = tbl + ((size_t)ss * 64 + j0) * 2;
      union { float4 v[4]; float a[16]; } cs;
      cs.v[0] = *(const float4*)(tb);
      cs.v[1] = *(const float4*)(tb + 4);
      cs.v[2] = *(const float4*)(tb + 8);
      cs.v[3] = *(const float4*)(tb + 12);
      s16x8 o0, o1;
#pragma unroll
      for (int k = 0; k < 8; ++k) {
        float c  = cs.a[2 * k];
        float sn = cs.a[2 * k + 1];
        float xjf  = bf2f((unsigned short)xj[k]);
        float xj6f = bf2f((unsigned short)xj6[k]);
        float x2j  = (2 * k < 8) ? bf2f((unsigned short)x2a[2 * k])
                                 : bf2f((unsigned short)x2b[2 * k - 8]);
        float x2j1 = (2 * k + 1 < 8) ? bf2f((unsigned short)x2a[2 * k + 1])
                                     : bf2f((unsigned short)x2b[2 * k + 1 - 8]);
        o0[k] = (short)f2bf(xjf * c - x2j1 * sn);
        o1[k] = (short)f2bf(xj6f * c + x2j * sn);
      }
      unsigned short* dstp;
      if (bx < 8) {
        int hh = bx * 2 + hl;
        dstp = Qo + ((size_t)(bb * NH + hh) * SEQ + ss) * HD;
      } else {
        int kvh = (bx - 8) * 2 + hl;
        dstp = Ko + ((size_t)(bb * NKV + kvh) * SEQ + ss) * HD;
      }
      *(s16x8*)(dstp + j0)      = o0;
      *(s16x8*)(dstp + 64 + j0) = o1;
    }
  } else {
    // ---- V region: transposed store [B][NKV][HD][S] ----
    int rbase = m0 + wm * 128 + rg4;
#pragma unroll
    for (int nf = 0; nf < 4; ++nf) {
      int gn = n0 + wn * 64 + nf * 16 + fr;
      int c = gn - 2560, kvh = c >> 7, d = c & 127;
#pragma unroll
      for (int mf = 0; mf < 8; ++mf) {
        int grow0 = rbase + mf * 16;
        int bb = grow0 >> 11, ss = grow0 & 2047;
        s16x4 pk;
#pragma unroll
        for (int r = 0; r < 4; ++r) pk[r] = (short)f2bf(acc[mf][nf][r]);
        *(s16x4*)(Vo + ((size_t)(bb * NKV + kvh) * HD + d) * SEQ + ss) = pk;
      }
    }
  }
#undef RING
}

// ---------------- O-proj GEMM v2: 256x128 tile, BK=32, 4-deep ring, counted vmcnt ----------------
__global__ __launch_bounds__(512, 1) void gemm_out(
    const unsigned short* __restrict__ A, const unsigned short* __restrict__ BT,
    float* __restrict__ C) {
  __shared__ __align__(16) unsigned short ldsA[4][8192];     // 256x32
  __shared__ __align__(16) unsigned short ldsB[4][4096];     // 128x32
  int tid = threadIdx.x, lane = tid & 63;
  int w = tid >> 6, wm = w >> 2, wn = w & 3;
  int lin = blockIdx.x;
  int swz = (lin & 7) * 32 + (lin >> 3);                     // 256 = 8 XCD x 32
  int bx = swz % 16, by = swz / 16;
  int m0 = by * 256, n0 = bx * 128;
  int fr = lane & 15, cg4 = lane >> 4, rg4 = (lane >> 4) * 4;

  int rS1 = tid >> 2,  cS1 = (tid & 3) ^ (rS1 & 3);
  int t2  = tid + 512;
  int rS2 = t2 >> 2,   cS2 = (t2 & 3) ^ (rS2 & 3);
  int rB  = tid >> 2,  cB  = (tid & 3) ^ (rB & 3);

  f32x4 acc[8][2] = {};

#pragma unroll
  for (int kt = 0; kt < 2; ++kt) {
    gload_lds16(A + (size_t)(m0 + rS1) * KDIM + kt * 32 + cS1 * 8,
                (char*)&ldsA[kt][0] + (size_t)tid * 16);
    gload_lds16(A + (size_t)(m0 + rS2) * KDIM + kt * 32 + cS2 * 8,
                (char*)&ldsA[kt][0] + (size_t)t2 * 16);
    gload_lds16(BT + (size_t)(n0 + rB) * KDIM + kt * 32 + cB * 8,
                (char*)&ldsB[kt][0] + (size_t)tid * 16);
  }

  const int NK = KDIM / 32;
  for (int kt = 0; kt < NK; ++kt) {
    int buf = kt & 3;
    if (kt == NK - 1) asm volatile("s_waitcnt vmcnt(0)" ::: "memory");
    else              asm volatile("s_waitcnt vmcnt(3)" ::: "memory");
    __builtin_amdgcn_s_barrier();

    const unsigned short* lA = &ldsA[buf][0];
    const unsigned short* lB = &ldsB[buf][0];
    s16x8 bfr[2], afr[4];
#pragma unroll
    for (int nf = 0; nf < 2; ++nf) {
      int rb = wn * 32 + nf * 16 + fr;
      bfr[nf] = *(const s16x8*)(lB + rb * 32 + (cg4 ^ (rb & 3)) * 8);
    }
#pragma unroll
    for (int mf = 0; mf < 4; ++mf) {
      int ra = wm * 128 + mf * 16 + fr;
      afr[mf] = *(const s16x8*)(lA + ra * 32 + (cg4 ^ (ra & 3)) * 8);
    }
    if (kt + 2 < NK) {
      int nb = (kt + 2) & 3, ko = (kt + 2) * 32;
      gload_lds16(A + (size_t)(m0 + rS1) * KDIM + ko + cS1 * 8,
                  (char*)&ldsA[nb][0] + (size_t)tid * 16);
      gload_lds16(A + (size_t)(m0 + rS2) * KDIM + ko + cS2 * 8,
                  (char*)&ldsA[nb][0] + (size_t)t2 * 16);
    }
    __builtin_amdgcn_s_setprio(1);
#pragma unroll
    for (int mf = 0; mf < 4; ++mf)
#pragma unroll
      for (int nf = 0; nf < 2; ++nf)
        acc[mf][nf] = MFMA16(afr[mf], bfr[nf], acc[mf][nf]);
    __builtin_amdgcn_s_setprio(0);
#pragma unroll
    for (int mf = 0; mf < 4; ++mf) {
      int ra = wm * 128 + (mf + 4) * 16 + fr;
      afr[mf] = *(const s16x8*)(lA + ra * 32 + (cg4 ^ (ra & 3)) * 8);
    }
    if (kt + 2 < NK) {
      int nb = (kt + 2) & 3, ko = (kt + 2) * 32;
      gload_lds16(BT + (size_t)(n0 + rB) * KDIM + ko + cB * 8,
                  (char*)&ldsB[nb][0] + (size_t)tid * 16);
    }
    __builtin_amdgcn_s_setprio(1);
#pragma unroll
    for (int mf = 0; mf < 4; ++mf)
#pragma unroll
      for (int nf = 0; nf < 2; ++nf)
        acc[mf + 4][nf] = MFMA16(afr[mf], bfr[nf], acc[mf + 4][nf]);
    __builtin_amdgcn_s_setprio(0);
  }

  int rbase = m0 + wm * 128 + rg4;
#pragma unroll
  for (int nf = 0; nf < 2; ++nf) {
    int gn = n0 + wn * 32 + nf * 16 + fr;
#pragma unroll
    for (int mf = 0; mf < 8; ++mf)
#pragma unroll
      for (int r = 0; r < 4; ++r)
        C[(size_t)(rbase + mf * 16 + r) * 2048 + gn] = acc[mf][nf][r];
  }
}

// ---------------- Flash attention v12: K+V double-buffered, ONE barrier/tile ----------------
__global__ __launch_bounds__(256, 2) void attn_fwd(
    const unsigned short* __restrict__ Q, const unsigned short* __restrict__ K,
    const unsigned short* __restrict__ VT, const float* __restrict__ mask,
    unsigned short* __restrict__ O) {
  __shared__ __align__(16) unsigned short kt_[2][64][136];
  __shared__ __align__(16) unsigned short vt_[2][128][68];
  __shared__ __align__(16) unsigned short pt_[4][16][36];

  int tid = threadIdx.x, lane = tid & 63, w = tid >> 6;
  int l = blockIdx.x;
  int grp = l & 7, slot = l >> 3;
  int hloc = slot & 3, qt = 31 - (slot >> 2);
  int b = grp >> 2, kvh = grp & 3, h = kvh * 4 + hloc;
  int qbase = qt * 64;
  int qw = qbase + w * 16;
  int fr = lane & 15, g = lane >> 4, kg = g * 8, rg = g * 4;

  const unsigned short* Qb = Q + (size_t)(b * NH + h) * SEQ * HD;
  const unsigned short* Kb = K + (size_t)(b * NKV + kvh) * SEQ * HD;
  const unsigned short* Vb = VT + (size_t)(b * NKV + kvh) * HD * SEQ;
  const float* mb = mask + (size_t)b * SEQ;

  int krow = tid >> 4, kpos = (tid & 15) * 8;
  const float sc2 = 0.12751744584812722f;
  const float L2E = 1.44269504088896f;
  int bS = b * SEQ;
  int ntiles = qt + 1;

  s16x8 aq[4];
#pragma unroll
  for (int dc = 0; dc < 4; ++dc)
    aq[dc] = *(const s16x8*)(Qb + (size_t)(qw + fr) * HD + dc * 32 + kg);

  f32x4 oacc[8] = {};
  float m_r = -3e38f, l_r = 0.f;

  s16x8 kreg[4], vreg[4];
#pragma unroll
  for (int i = 0; i < 4; ++i)
    kreg[i] = *(const s16x8*)(Kb + (size_t)(krow + i * 16) * HD + kpos);
#pragma unroll
  for (int i = 0; i < 4; ++i) {
    int c = tid + 256 * i;
    vreg[i] = *(const s16x8*)(Vb + (size_t)(c >> 3) * SEQ + (c & 7) * 8);
  }
#pragma unroll
  for (int i = 0; i < 4; ++i)
    *(s16x8*)(&kt_[0][krow + i * 16][kpos]) = kreg[i];
#pragma unroll
  for (int i = 0; i < 4; ++i) {
    int c = tid + 256 * i;
    *(s16x8*)(&vt_[0][c >> 3][(c & 7) * 8]) = vreg[i];
  }
  if (ntiles > 1) {
#pragma unroll
    for (int i = 0; i < 4; ++i)
      kreg[i] = *(const s16x8*)(Kb + (size_t)(64 + krow + i * 16) * HD + kpos);
#pragma unroll
    for (int i = 0; i < 4; ++i) {
      int c = tid + 256 * i;
      vreg[i] = *(const s16x8*)(Vb + (size_t)(c >> 3) * SEQ + 64 + (c & 7) * 8);
    }
  }
  BARRIER_LDS();

  for (int t = 0; t < ntiles; ++t) {
    int kv0 = t * 64;
    int cur = t & 1;
    bool diag = (t == qt);

    if (t + 1 < ntiles) {
#pragma unroll
      for (int i = 0; i < 4; ++i)
        *(s16x8*)(&kt_[cur ^ 1][krow + i * 16][kpos]) = kreg[i];
#pragma unroll
      for (int i = 0; i < 4; ++i) {
        int c = tid + 256 * i;
        *(s16x8*)(&vt_[cur ^ 1][c >> 3][(c & 7) * 8]) = vreg[i];
      }
      if (t + 2 < ntiles) {
#pragma unroll
        for (int i = 0; i < 4; ++i)
          kreg[i] = *(const s16x8*)(Kb + (size_t)(kv0 + 128 + krow + i * 16) * HD + kpos);
#pragma unroll
        for (int i = 0; i < 4; ++i) {
          int c = tid + 256 * i;
          vreg[i] = *(const s16x8*)(Vb + (size_t)(c >> 3) * SEQ + kv0 + 128 + (c & 7) * 8);
        }
      }
    }

    f32x4 sf[4];
    __builtin_amdgcn_s_setprio(1);
#pragma unroll
    for (int mk = 0; mk < 4; ++mk) {
      s16x8 ak[4];
#pragma unroll
      for (int dc = 0; dc < 4; ++dc)
        ak[dc] = *(const s16x8*)(&kt_[cur][mk * 16 + fr][dc * 32 + kg]);
      sf[mk] = f32x4{0.f, 0.f, 0.f, 0.f};
#pragma unroll
      for (int dc = 0; dc < 4; ++dc)
        sf[mk] = MFMA16(ak[dc], aq[dc], sf[mk]);
    }
    __builtin_amdgcn_s_setprio(0);

#pragma unroll
    for (int mk = 0; mk < 4; ++mk) {
      float4 mv = *(const float4*)(mb + kv0 + mk * 16 + rg);
      float mvr[4] = {mv.x * L2E, mv.y * L2E, mv.z * L2E, mv.w * L2E};
      if (diag) {
#pragma unroll
        for (int r = 0; r < 4; ++r) {
          int kv = kv0 + mk * 16 + rg + r;
          float v = sf[mk][r] * sc2 + mvr[r];
          sf[mk][r] = (kv <= qw + fr) ? v : -3e38f;
        }
      } else {
#pragma unroll
        for (int r = 0; r < 4; ++r)
          sf[mk][r] = sf[mk][r] * sc2 + mvr[r];
      }
    }

    float pm01a = fmaxf(sf[0][0], sf[0][1]), pm01b = fmaxf(sf[0][2], sf[0][3]);
    float pm11a = fmaxf(sf[1][0], sf[1][1]), pm11b = fmaxf(sf[1][2], sf[1][3]);
    float pm21a = fmaxf(sf[2][0], sf[2][1]), pm21b = fmaxf(sf[2][2], sf[2][3]);
    float pm31a = fmaxf(sf[3][0], sf[3][1]), pm31b = fmaxf(sf[3][2], sf[3][3]);
    float pm0 = fmaxf(pm01a, pm01b), pm1 = fmaxf(pm11a, pm11b);
    float pm2 = fmaxf(pm21a, pm21b), pm3 = fmaxf(pm31a, pm31b);
    float pm = fmaxf(fmaxf(pm0, pm1), fmaxf(pm2, pm3));
    pm = fmaxf(pm, __shfl_xor(pm, 16, 64));
    pm = fmaxf(pm, __shfl_xor(pm, 32, 64));
    if (!__all(pm - m_r <= 8.0f)) {
      float mo = m_r;
      float mn = fmaxf(mo, pm);
      float al = exp2f(mo - mn);
      m_r = mn;
      l_r *= al;
#pragma unroll
      for (int r = 0; r < 4; ++r) {
        float ar = __shfl(al, rg + r, 16);
#pragma unroll
        for (int od = 0; od < 8; ++od) oacc[od][r] *= ar;
      }
    }
    float rs = 0.f;
#pragma unroll
    for (int mk = 0; mk < 4; ++mk)
#pragma unroll
      for (int r = 0; r < 4; ++r) {
        float ppv = exp2f(sf[mk][r] - m_r);
        sf[mk][r] = ppv;
        rs += ppv;
      }
    rs += __shfl_xor(rs, 16, 64);
    rs += __shfl_xor(rs, 32, 64);
    l_r += rs;

#pragma unroll
    for (int kk = 0; kk < 2; ++kk) {
#pragma unroll
      for (int mh = 0; mh < 2; ++mh) {
        int mk = kk * 2 + mh;
        s16x4 pk;
#pragma unroll
        for (int r = 0; r < 4; ++r) pk[r] = (short)f2bf(sf[mk][r]);
        *(s16x4*)(&pt_[w][fr][mh * 16 + rg]) = pk;
      }
      s16x8 ap = *(const s16x8*)(&pt_[w][fr][kg]);
      __builtin_amdgcn_s_setprio(1);
#pragma unroll
      for (int od = 0; od < 8; ++od) {
        s16x8 bv = *(const s16x8*)(&vt_[cur][od * 16 + fr][kk * 32 + kg]);
        oacc[od] = MFMA16(ap, bv, oacc[od]);
      }
      __builtin_amdgcn_s_setprio(0);
    }

    BARRIER_LDS();
  }

  float iv = 1.0f / l_r;
  float ivr[4];
#pragma unroll
  for (int r = 0; r < 4; ++r) ivr[r] = __shfl(iv, rg + r, 16);
#pragma unroll
  for (int r = 0; r < 4; ++r) {
    unsigned short* op = O + (size_t)(bS + qw + rg + r) * 2048 + h * 128 + fr;
#pragma unroll
    for (int od = 0; od < 8; ++od)
      op[od * 16] = f2bf(oacc[od][r] * ivr[r]);
  }
}

extern "C" void kernel_launch(void* const* d_in, const int* in_sizes, int n_in,
                              void* d_out, int out_size, void* d_ws, size_t ws_size,
                              hipStream_t stream) {
  const float* hidden = (const float*)d_in[0];
  const float* mask   = (const float*)d_in[1];
  const float* Wq     = (const float*)d_in[2];
  const float* Wk     = (const float*)d_in[3];
  const float* Wv     = (const float*)d_in[4];
  const float* Wo     = (const float*)d_in[5];
  float* out = (float*)d_out;

  char* ws = (char*)d_ws;
  unsigned short* BT  = (unsigned short*)(ws);                 // 3072x2048 bf16
  unsigned short* WoT = (unsigned short*)(ws + 12582912);      // 2048x2048 bf16
  unsigned short* Qb  = (unsigned short*)(ws + 20971520);      // [B][NH][S][HD]
  unsigned short* Kb  = (unsigned short*)(ws + 37748736);      // [B][NKV][S][HD]
  unsigned short* VT  = (unsigned short*)(ws + 41943040);      // [B][NKV][HD][S]
  unsigned short* AO  = (unsigned short*)(ws + 46137344);      // [MROWS][2048] bf16
  float*          tbl = (float*)(ws + 62914560);               // [S][64][2] f32
  unsigned short* Ab  = AO;  // hidden as bf16; dead before attn writes AO

  prep_all<<<dim3(14848), 256, 0, stream>>>(hidden, Wq, Wk, Wv, Wo, Ab, BT, WoT, tbl);
  gemm_qkv<<<dim3(192), 512, 0, stream>>>(Ab, BT, tbl, Qb, Kb, VT);
  attn_fwd<<<dim3(1024), 256, 0, stream>>>(Qb, Kb, VT, mask, AO);
  gemm_out<<<dim3(256), 512, 0, stream>>>(AO, WoT, out);
}

// Round 17
// 201.570 us; speedup vs baseline: 1.2146x; 1.0128x over previous
//
#include <hip/hip_runtime.h>
#include <hip/hip_bf16.h>

#define BATCH 2
#define SEQ   2048
#define NH    16
#define NKV   4
#define HD    128
#define KDIM  2048
#define MROWS 4096
#define NQKV  3072

typedef __attribute__((ext_vector_type(8))) short  s16x8;
typedef __attribute__((ext_vector_type(4))) short  s16x4;
typedef __attribute__((ext_vector_type(4))) float  f32x4;
typedef __attribute__((ext_vector_type(8))) __bf16 b16x8;

// barrier that drains LDS ops only -- leaves global prefetch loads in flight
#define BARRIER_LDS() do { \
    asm volatile("s_waitcnt lgkmcnt(0)" ::: "memory"); \
    __builtin_amdgcn_s_barrier(); \
  } while (0)

__device__ __forceinline__ unsigned short f2bf(float f) {
  __hip_bfloat16 h = __float2bfloat16(f);
  return *reinterpret_cast<unsigned short*>(&h);
}
__device__ __forceinline__ float bf2f(unsigned short h) {
  union { unsigned int u; float f; } x; x.u = ((unsigned int)h) << 16;
  return x.f;
}

// pack two f32 -> one u32 of two bf16 (TRUNCATION) in a single v_perm_b32
__device__ __forceinline__ unsigned pack2_trunc(float hif, float lof) {
  unsigned r, sel = 0x07060302u;
  asm("v_perm_b32 %0, %1, %2, %3" : "=v"(r) : "v"(hif), "v"(lof), "v"(sel));
  return r;
}
__device__ __forceinline__ float max3f(float a, float b, float c) {
  float r;
  asm("v_max3_f32 %0, %1, %2, %3" : "=v"(r) : "v"(a), "v"(b), "v"(c));
  return r;
}

__device__ __forceinline__ f32x4 MFMA16(s16x8 a, s16x8 b, f32x4 c) {
  return __builtin_amdgcn_mfma_f32_16x16x32_bf16(
      __builtin_bit_cast(b16x8, a), __builtin_bit_cast(b16x8, b), c, 0, 0, 0);
}

__device__ __forceinline__ void gload_lds16(const void* g, void* lds) {
  __builtin_amdgcn_global_load_lds(
      (const __attribute__((address_space(1))) void*)g,
      (__attribute__((address_space(3))) void*)lds, 16, 0, 0);
}

// ---------------- fused prep: hidden->bf16 + weight transposes + rope table + scaled mask ----------------
// regions: [0,10240) weights; [10240,14336) conv; [14336,14848) rope table; [14848,14864) mask*log2e
__global__ __launch_bounds__(256) void prep_all(
    const float* __restrict__ hidden,
    const float* __restrict__ Wq, const float* __restrict__ Wk,
    const float* __restrict__ Wv, const float* __restrict__ Wo,
    const float* __restrict__ mask,
    unsigned short* __restrict__ Ab, unsigned short* __restrict__ BT,
    unsigned short* __restrict__ WoT, float* __restrict__ tbl,
    float* __restrict__ maskS) {
  __shared__ float tile[32][33];
  int bid = blockIdx.x;
  if (bid < 10240) {
    int sub = bid % 160, ky = bid / 160;
    const float* W; unsigned short* WT; int Nd, nb;
    if (sub < 64)       { W = Wq; WT = BT;                       Nd = 2048; nb = sub; }
    else if (sub < 80)  { W = Wk; WT = BT + (size_t)2048 * KDIM; Nd = 512;  nb = sub - 64; }
    else if (sub < 96)  { W = Wv; WT = BT + (size_t)2560 * KDIM; Nd = 512;  nb = sub - 80; }
    else                { W = Wo; WT = WoT;                      Nd = 2048; nb = sub - 96; }
    int n0 = nb * 32, k0 = ky * 32;
    int tx = threadIdx.x & 31, ty = threadIdx.x >> 5;
#pragma unroll
    for (int i = 0; i < 4; ++i)
      tile[ty + i * 8][tx] = W[(size_t)(k0 + ty + i * 8) * Nd + n0 + tx];
    __syncthreads();
#pragma unroll
    for (int i = 0; i < 4; ++i)
      WT[(size_t)(n0 + ty + i * 8) * KDIM + k0 + tx] = f2bf(tile[tx][ty + i * 8]);
  } else if (bid < 14336) {
    int i = (bid - 10240) * 256 + threadIdx.x;
    const float4 a = ((const float4*)hidden)[2 * i];
    const float4 b = ((const float4*)hidden)[2 * i + 1];
    s16x8 o;
    o[0] = (short)f2bf(a.x); o[1] = (short)f2bf(a.y);
    o[2] = (short)f2bf(a.z); o[3] = (short)f2bf(a.w);
    o[4] = (short)f2bf(b.x); o[5] = (short)f2bf(b.y);
    o[6] = (short)f2bf(b.z); o[7] = (short)f2bf(b.w);
    ((s16x8*)Ab)[i] = o;
  } else if (bid < 14848) {
    int i = (bid - 14336) * 256 + threadIdx.x;
    int s = i >> 6, j = i & 63;
    float inv = powf(10000.0f, -(float)(2 * j) * (1.0f / 128.0f));
    float f = (float)s * inv;
    tbl[2 * i]     = cosf(f);
    tbl[2 * i + 1] = sinf(f);
  } else {
    int i = (bid - 14848) * 256 + threadIdx.x;   // < BATCH*SEQ
    maskS[i] = mask[i] * 1.44269504088896f;
  }
}

// ---------------- QKV GEMM v3: 256x256, BK=32, 4-deep ring, counted vmcnt, fused RoPE ----------------
__global__ __launch_bounds__(512, 2) void gemm_qkv(
    const unsigned short* __restrict__ A, const unsigned short* __restrict__ BT,
    const float* __restrict__ tbl,
    unsigned short* __restrict__ Qo, unsigned short* __restrict__ Ko,
    unsigned short* __restrict__ Vo) {
  __shared__ __align__(16) unsigned short lds_[66560];   // ring 4x2x8192 = 65536; scratch 256x260
#define RING(buf, ab) (lds_ + (((buf) * 2 + (ab)) << 13))
  int tid = threadIdx.x, lane = tid & 63;
  int w = tid >> 6, wm = w >> 2, wn = w & 3;
  int lin = blockIdx.x;
  int swz = (lin & 7) * 24 + (lin >> 3);                 // 192 = 8 XCD x 24
  int bx = swz % 12, by = swz / 12;
  int m0 = by * 256, n0 = bx * 256;
  int fr = lane & 15, cg4 = lane >> 4, rg4 = (lane >> 4) * 4;

  int rS1 = tid >> 2,        cS1 = (tid & 3) ^ (rS1 & 3);
  int t2  = tid + 512;
  int rS2 = t2 >> 2,         cS2 = (t2 & 3) ^ (rS2 & 3);

  f32x4 acc[8][4] = {};

#pragma unroll
  for (int kt = 0; kt < 2; ++kt) {
    gload_lds16(A + (size_t)(m0 + rS1) * KDIM + kt * 32 + cS1 * 8,
                (char*)RING(kt, 0) + (size_t)tid * 16);
    gload_lds16(A + (size_t)(m0 + rS2) * KDIM + kt * 32 + cS2 * 8,
                (char*)RING(kt, 0) + (size_t)t2 * 16);
    gload_lds16(BT + (size_t)(n0 + rS1) * KDIM + kt * 32 + cS1 * 8,
                (char*)RING(kt, 1) + (size_t)tid * 16);
    gload_lds16(BT + (size_t)(n0 + rS2) * KDIM + kt * 32 + cS2 * 8,
                (char*)RING(kt, 1) + (size_t)t2 * 16);
  }

  const int NK = KDIM / 32;
  for (int kt = 0; kt < NK; ++kt) {
    int buf = kt & 3;
    if (kt == NK - 1) asm volatile("s_waitcnt vmcnt(0)" ::: "memory");
    else              asm volatile("s_waitcnt vmcnt(4)" ::: "memory");
    __builtin_amdgcn_s_barrier();

    const unsigned short* lA = RING(buf, 0);
    const unsigned short* lB = RING(buf, 1);
    s16x8 bfr[4], afr[4];
#pragma unroll
    for (int nf = 0; nf < 4; ++nf) {
      int rb = wn * 64 + nf * 16 + fr;
      bfr[nf] = *(const s16x8*)(lB + rb * 32 + (cg4 ^ (rb & 3)) * 8);
    }
#pragma unroll
    for (int mf = 0; mf < 4; ++mf) {
      int ra = wm * 128 + mf * 16 + fr;
      afr[mf] = *(const s16x8*)(lA + ra * 32 + (cg4 ^ (ra & 3)) * 8);
    }
    if (kt + 2 < NK) {
      int nb = (kt + 2) & 3, ko = (kt + 2) * 32;
      gload_lds16(A + (size_t)(m0 + rS1) * KDIM + ko + cS1 * 8,
                  (char*)RING(nb, 0) + (size_t)tid * 16);
      gload_lds16(A + (size_t)(m0 + rS2) * KDIM + ko + cS2 * 8,
                  (char*)RING(nb, 0) + (size_t)t2 * 16);
    }
    __builtin_amdgcn_s_setprio(1);
#pragma unroll
    for (int mf = 0; mf < 4; ++mf)
#pragma unroll
      for (int nf = 0; nf < 4; ++nf)
        acc[mf][nf] = MFMA16(afr[mf], bfr[nf], acc[mf][nf]);
    __builtin_amdgcn_s_setprio(0);
#pragma unroll
    for (int mf = 0; mf < 4; ++mf) {
      int ra = wm * 128 + (mf + 4) * 16 + fr;
      afr[mf] = *(const s16x8*)(lA + ra * 32 + (cg4 ^ (ra & 3)) * 8);
    }
    if (kt + 2 < NK) {
      int nb = (kt + 2) & 3, ko = (kt + 2) * 32;
      gload_lds16(BT + (size_t)(n0 + rS1) * KDIM + ko + cS1 * 8,
                  (char*)RING(nb, 1) + (size_t)tid * 16);
      gload_lds16(BT + (size_t)(n0 + rS2) * KDIM + ko + cS2 * 8,
                  (char*)RING(nb, 1) + (size_t)t2 * 16);
    }
    __builtin_amdgcn_s_setprio(1);
#pragma unroll
    for (int mf = 0; mf < 4; ++mf)
#pragma unroll
      for (int nf = 0; nf < 4; ++nf)
        acc[mf + 4][nf] = MFMA16(afr[mf], bfr[nf], acc[mf + 4][nf]);
    __builtin_amdgcn_s_setprio(0);
  }

  if (bx < 10) {
    // ---- Q/K region: dump acc -> scratch, barrier, rope+store ----
    BARRIER_LDS();
    unsigned short* sc_ = lds_;          // 256 rows x 260 (padded) bf16
#pragma unroll
    for (int mf = 0; mf < 8; ++mf)
#pragma unroll
      for (int nf = 0; nf < 4; ++nf)
#pragma unroll
        for (int r = 0; r < 4; ++r)
          sc_[(wm * 128 + mf * 16 + rg4 + r) * 260 + wn * 64 + nf * 16 + fr] =
              f2bf(acc[mf][nf][r]);
    BARRIER_LDS();

#pragma unroll
    for (int i = 0; i < 8; ++i) {
      int t = tid + 512 * i;
      int row = t >> 4, rem = t & 15;
      int hl = rem >> 3, j0 = (rem & 7) * 8;
      int grow = m0 + row, bb = grow >> 11, ss = grow & 2047;
      const unsigned short* xb = sc_ + row * 260 + hl * 128;
      s16x8 xj  = *(const s16x8*)(xb + j0);
      s16x8 xj6 = *(const s16x8*)(xb + 64 + j0);
      s16x8 x2a = *(const s16x8*)(xb + 2 * j0);
      s16x8 x2b = *(const s16x8*)(xb + 2 * j0 + 8);
      const float* tb = tbl + ((size_t)ss * 64 + j0) * 2;
      union { float4 v[4]; float a[16]; } cs;
      cs.v[0] = *(const float4*)(tb);
      cs.v[1] = *(const float4*)(tb + 4);
      cs.v[2] = *(const float4*)(tb + 8);
      cs.v[3] = *(const float4*)(tb + 12);
      s16x8 o0, o1;
#pragma unroll
      for (int k = 0; k < 8; ++k) {
        float c  = cs.a[2 * k];
        float sn = cs.a[2 * k + 1];
        float xjf  = bf2f((unsigned short)xj[k]);
        float xj6f = bf2f((unsigned short)xj6[k]);
        float x2j  = (2 * k < 8) ? bf2f((unsigned short)x2a[2 * k])
                                 : bf2f((unsigned short)x2b[2 * k - 8]);
        float x2j1 = (2 * k + 1 < 8) ? bf2f((unsigned short)x2a[2 * k + 1])
                                     : bf2f((unsigned short)x2b[2 * k + 1 - 8]);
        o0[k] = (short)f2bf(xjf * c - x2j1 * sn);
        o1[k] = (short)f2bf(xj6f * c + x2j * sn);
      }
      unsigned short* dstp;
      if (bx < 8) {
        int hh = bx * 2 + hl;
        dstp = Qo + ((size_t)(bb * NH + hh) * SEQ + ss) * HD;
      } else {
        int kvh = (bx - 8) * 2 + hl;
        dstp = Ko + ((size_t)(bb * NKV + kvh) * SEQ + ss) * HD;
      }
      *(s16x8*)(dstp + j0)      = o0;
      *(s16x8*)(dstp + 64 + j0) = o1;
    }
  } else {
    // ---- V region: transposed store [B][NKV][HD][S] ----
    int rbase = m0 + wm * 128 + rg4;
#pragma unroll
    for (int nf = 0; nf < 4; ++nf) {
      int gn = n0 + wn * 64 + nf * 16 + fr;
      int c = gn - 2560, kvh = c >> 7, d = c & 127;
#pragma unroll
      for (int mf = 0; mf < 8; ++mf) {
        int grow0 = rbase + mf * 16;
        int bb = grow0 >> 11, ss = grow0 & 2047;
        s16x4 pk;
#pragma unroll
        for (int r = 0; r < 4; ++r) pk[r] = (short)f2bf(acc[mf][nf][r]);
        *(s16x4*)(Vo + ((size_t)(bb * NKV + kvh) * HD + d) * SEQ + ss) = pk;
      }
    }
  }
#undef RING
}

// ---------------- O-proj GEMM v2: 256x128 tile, BK=32, 4-deep ring, counted vmcnt ----------------
__global__ __launch_bounds__(512, 1) void gemm_out(
    const unsigned short* __restrict__ A, const unsigned short* __restrict__ BT,
    float* __restrict__ C) {
  __shared__ __align__(16) unsigned short ldsA[4][8192];     // 256x32
  __shared__ __align__(16) unsigned short ldsB[4][4096];     // 128x32
  int tid = threadIdx.x, lane = tid & 63;
  int w = tid >> 6, wm = w >> 2, wn = w & 3;
  int lin = blockIdx.x;
  int swz = (lin & 7) * 32 + (lin >> 3);                     // 256 = 8 XCD x 32
  int bx = swz % 16, by = swz / 16;
  int m0 = by * 256, n0 = bx * 128;
  int fr = lane & 15, cg4 = lane >> 4, rg4 = (lane >> 4) * 4;

  int rS1 = tid >> 2,  cS1 = (tid & 3) ^ (rS1 & 3);
  int t2  = tid + 512;
  int rS2 = t2 >> 2,   cS2 = (t2 & 3) ^ (rS2 & 3);
  int rB  = tid >> 2,  cB  = (tid & 3) ^ (rB & 3);

  f32x4 acc[8][2] = {};

#pragma unroll
  for (int kt = 0; kt < 2; ++kt) {
    gload_lds16(A + (size_t)(m0 + rS1) * KDIM + kt * 32 + cS1 * 8,
                (char*)&ldsA[kt][0] + (size_t)tid * 16);
    gload_lds16(A + (size_t)(m0 + rS2) * KDIM + kt * 32 + cS2 * 8,
                (char*)&ldsA[kt][0] + (size_t)t2 * 16);
    gload_lds16(BT + (size_t)(n0 + rB) * KDIM + kt * 32 + cB * 8,
                (char*)&ldsB[kt][0] + (size_t)tid * 16);
  }

  const int NK = KDIM / 32;
  for (int kt = 0; kt < NK; ++kt) {
    int buf = kt & 3;
    if (kt == NK - 1) asm volatile("s_waitcnt vmcnt(0)" ::: "memory");
    else              asm volatile("s_waitcnt vmcnt(3)" ::: "memory");
    __builtin_amdgcn_s_barrier();

    const unsigned short* lA = &ldsA[buf][0];
    const unsigned short* lB = &ldsB[buf][0];
    s16x8 bfr[2], afr[4];
#pragma unroll
    for (int nf = 0; nf < 2; ++nf) {
      int rb = wn * 32 + nf * 16 + fr;
      bfr[nf] = *(const s16x8*)(lB + rb * 32 + (cg4 ^ (rb & 3)) * 8);
    }
#pragma unroll
    for (int mf = 0; mf < 4; ++mf) {
      int ra = wm * 128 + mf * 16 + fr;
      afr[mf] = *(const s16x8*)(lA + ra * 32 + (cg4 ^ (ra & 3)) * 8);
    }
    if (kt + 2 < NK) {
      int nb = (kt + 2) & 3, ko = (kt + 2) * 32;
      gload_lds16(A + (size_t)(m0 + rS1) * KDIM + ko + cS1 * 8,
                  (char*)&ldsA[nb][0] + (size_t)tid * 16);
      gload_lds16(A + (size_t)(m0 + rS2) * KDIM + ko + cS2 * 8,
                  (char*)&ldsA[nb][0] + (size_t)t2 * 16);
    }
    __builtin_amdgcn_s_setprio(1);
#pragma unroll
    for (int mf = 0; mf < 4; ++mf)
#pragma unroll
      for (int nf = 0; nf < 2; ++nf)
        acc[mf][nf] = MFMA16(afr[mf], bfr[nf], acc[mf][nf]);
    __builtin_amdgcn_s_setprio(0);
#pragma unroll
    for (int mf = 0; mf < 4; ++mf) {
      int ra = wm * 128 + (mf + 4) * 16 + fr;
      afr[mf] = *(const s16x8*)(lA + ra * 32 + (cg4 ^ (ra & 3)) * 8);
    }
    if (kt + 2 < NK) {
      int nb = (kt + 2) & 3, ko = (kt + 2) * 32;
      gload_lds16(BT + (size_t)(n0 + rB) * KDIM + ko + cB * 8,
                  (char*)&ldsB[nb][0] + (size_t)tid * 16);
    }
    __builtin_amdgcn_s_setprio(1);
#pragma unroll
    for (int mf = 0; mf < 4; ++mf)
#pragma unroll
      for (int nf = 0; nf < 2; ++nf)
        acc[mf + 4][nf] = MFMA16(afr[mf], bfr[nf], acc[mf + 4][nf]);
    __builtin_amdgcn_s_setprio(0);
  }

  int rbase = m0 + wm * 128 + rg4;
#pragma unroll
  for (int nf = 0; nf < 2; ++nf) {
    int gn = n0 + wn * 32 + nf * 16 + fr;
#pragma unroll
    for (int mf = 0; mf < 8; ++mf)
#pragma unroll
      for (int r = 0; r < 4; ++r)
        C[(size_t)(rbase + mf * 16 + r) * 2048 + gn] = acc[mf][nf][r];
  }
}

// ---------------- Flash attention v14: v12 + perm-pack P + max3 tree + pre-scaled mask ----------------
__global__ __launch_bounds__(256, 2) void attn_fwd(
    const unsigned short* __restrict__ Q, const unsigned short* __restrict__ K,
    const unsigned short* __restrict__ VT, const float* __restrict__ maskS,
    unsigned short* __restrict__ O) {
  __shared__ __align__(16) unsigned short kt_[2][64][136];
  __shared__ __align__(16) unsigned short vt_[2][128][68];
  __shared__ __align__(16) unsigned short pt_[4][16][36];

  int tid = threadIdx.x, lane = tid & 63, w = tid >> 6;
  int l = blockIdx.x;
  int grp = l & 7, slot = l >> 3;
  int hloc = slot & 3, qt = 31 - (slot >> 2);
  int b = grp >> 2, kvh = grp & 3, h = kvh * 4 + hloc;
  int qbase = qt * 64;
  int qw = qbase + w * 16;
  int fr = lane & 15, g = lane >> 4, kg = g * 8, rg = g * 4;

  const unsigned short* Qb = Q + (size_t)(b * NH + h) * SEQ * HD;
  const unsigned short* Kb = K + (size_t)(b * NKV + kvh) * SEQ * HD;
  const unsigned short* Vb = VT + (size_t)(b * NKV + kvh) * HD * SEQ;
  const float* mb = maskS + (size_t)b * SEQ;   // already * log2(e)

  int krow = tid >> 4, kpos = (tid & 15) * 8;
  const float sc2 = 0.12751744584812722f;      // 1/sqrt(128) * log2(e)
  int bS = b * SEQ;
  int ntiles = qt + 1;

  s16x8 aq[4];
#pragma unroll
  for (int dc = 0; dc < 4; ++dc)
    aq[dc] = *(const s16x8*)(Qb + (size_t)(qw + fr) * HD + dc * 32 + kg);

  f32x4 oacc[8] = {};
  float m_r = -3e38f, l_r = 0.f;

  s16x8 kreg[4], vreg[4];
#pragma unroll
  for (int i = 0; i < 4; ++i)
    kreg[i] = *(const s16x8*)(Kb + (size_t)(krow + i * 16) * HD + kpos);
#pragma unroll
  for (int i = 0; i < 4; ++i) {
    int c = tid + 256 * i;
    vreg[i] = *(const s16x8*)(Vb + (size_t)(c >> 3) * SEQ + (c & 7) * 8);
  }
#pragma unroll
  for (int i = 0; i < 4; ++i)
    *(s16x8*)(&kt_[0][krow + i * 16][kpos]) = kreg[i];
#pragma unroll
  for (int i = 0; i < 4; ++i) {
    int c = tid + 256 * i;
    *(s16x8*)(&vt_[0][c >> 3][(c & 7) * 8]) = vreg[i];
  }
  if (ntiles > 1) {
#pragma unroll
    for (int i = 0; i < 4; ++i)
      kreg[i] = *(const s16x8*)(Kb + (size_t)(64 + krow + i * 16) * HD + kpos);
#pragma unroll
    for (int i = 0; i < 4; ++i) {
      int c = tid + 256 * i;
      vreg[i] = *(const s16x8*)(Vb + (size_t)(c >> 3) * SEQ + 64 + (c & 7) * 8);
    }
  }
  BARRIER_LDS();

  for (int t = 0; t < ntiles; ++t) {
    int kv0 = t * 64;
    int cur = t & 1;
    bool diag = (t == qt);

    if (t + 1 < ntiles) {
#pragma unroll
      for (int i = 0; i < 4; ++i)
        *(s16x8*)(&kt_[cur ^ 1][krow + i * 16][kpos]) = kreg[i];
#pragma unroll
      for (int i = 0; i < 4; ++i) {
        int c = tid + 256 * i;
        *(s16x8*)(&vt_[cur ^ 1][c >> 3][(c & 7) * 8]) = vreg[i];
      }
      if (t + 2 < ntiles) {
#pragma unroll
        for (int i = 0; i < 4; ++i)
          kreg[i] = *(const s16x8*)(Kb + (size_t)(kv0 + 128 + krow + i * 16) * HD + kpos);
#pragma unroll
        for (int i = 0; i < 4; ++i) {
          int c = tid + 256 * i;
          vreg[i] = *(const s16x8*)(Vb + (size_t)(c >> 3) * SEQ + kv0 + 128 + (c & 7) * 8);
        }
      }
    }

    f32x4 sf[4];
    __builtin_amdgcn_s_setprio(1);
#pragma unroll
    for (int mk = 0; mk < 4; ++mk) {
      s16x8 ak[4];
#pragma unroll
      for (int dc = 0; dc < 4; ++dc)
        ak[dc] = *(const s16x8*)(&kt_[cur][mk * 16 + fr][dc * 32 + kg]);
      sf[mk] = f32x4{0.f, 0.f, 0.f, 0.f};
#pragma unroll
      for (int dc = 0; dc < 4; ++dc)
        sf[mk] = MFMA16(ak[dc], aq[dc], sf[mk]);
    }
    __builtin_amdgcn_s_setprio(0);

    // scale + pre-scaled mask; causal select only on diagonal tile
#pragma unroll
    for (int mk = 0; mk < 4; ++mk) {
      float4 mv = *(const float4*)(mb + kv0 + mk * 16 + rg);
      float mvr[4] = {mv.x, mv.y, mv.z, mv.w};
      if (diag) {
#pragma unroll
        for (int r = 0; r < 4; ++r) {
          int kv = kv0 + mk * 16 + rg + r;
          float v = sf[mk][r] * sc2 + mvr[r];
          sf[mk][r] = (kv <= qw + fr) ? v : -3e38f;
        }
      } else {
#pragma unroll
        for (int r = 0; r < 4; ++r)
          sf[mk][r] = sf[mk][r] * sc2 + mvr[r];
      }
    }

    // online softmax (exp2 domain); max3 tree
    float m0_ = max3f(sf[0][0], sf[0][1], sf[0][2]);
    float m1_ = max3f(sf[0][3], sf[1][0], sf[1][1]);
    float m2_ = max3f(sf[1][2], sf[1][3], sf[2][0]);
    float m3_ = max3f(sf[2][1], sf[2][2], sf[2][3]);
    float m4_ = max3f(sf[3][0], sf[3][1], sf[3][2]);
    float ma_ = max3f(m0_, m1_, m2_);
    float mb_ = max3f(m3_, m4_, sf[3][3]);
    float pm = fmaxf(ma_, mb_);
    pm = fmaxf(pm, __shfl_xor(pm, 16, 64));
    pm = fmaxf(pm, __shfl_xor(pm, 32, 64));
    if (!__all(pm - m_r <= 8.0f)) {
      float mo = m_r;
      float mn = fmaxf(mo, pm);
      float al = exp2f(mo - mn);
      m_r = mn;
      l_r *= al;
#pragma unroll
      for (int r = 0; r < 4; ++r) {
        float ar = __shfl(al, rg + r, 16);
#pragma unroll
        for (int od = 0; od < 8; ++od) oacc[od][r] *= ar;
      }
    }
    float rs = 0.f;
#pragma unroll
    for (int mk = 0; mk < 4; ++mk)
#pragma unroll
      for (int r = 0; r < 4; ++r) {
        float ppv = exp2f(sf[mk][r] - m_r);
        sf[mk][r] = ppv;
        rs += ppv;
      }
    rs += __shfl_xor(rs, 16, 64);
    rs += __shfl_xor(rs, 32, 64);
    l_r += rs;

    // PV: P -> pt_ via single-op perm-pack (truncation; P in (0,1])
#pragma unroll
    for (int kk = 0; kk < 2; ++kk) {
#pragma unroll
      for (int mh = 0; mh < 2; ++mh) {
        int mk = kk * 2 + mh;
        unsigned w0 = pack2_trunc(sf[mk][1], sf[mk][0]);
        unsigned w1 = pack2_trunc(sf[mk][3], sf[mk][2]);
        uint2 pk2; pk2.x = w0; pk2.y = w1;
        *(uint2*)(&pt_[w][fr][mh * 16 + rg]) = pk2;
      }
      s16x8 ap = *(const s16x8*)(&pt_[w][fr][kg]);
      __builtin_amdgcn_s_setprio(1);
#pragma unroll
      for (int od = 0; od < 8; ++od) {
        s16x8 bv = *(const s16x8*)(&vt_[cur][od * 16 + fr][kk * 32 + kg]);
        oacc[od] = MFMA16(ap, bv, oacc[od]);
      }
      __builtin_amdgcn_s_setprio(0);
    }

    BARRIER_LDS();
  }

  float iv = 1.0f / l_r;
  float ivr[4];
#pragma unroll
  for (int r = 0; r < 4; ++r) ivr[r] = __shfl(iv, rg + r, 16);
#pragma unroll
  for (int r = 0; r < 4; ++r) {
    unsigned short* op = O + (size_t)(bS + qw + rg + r) * 2048 + h * 128 + fr;
#pragma unroll
    for (int od = 0; od < 8; ++od)
      op[od * 16] = f2bf(oacc[od][r] * ivr[r]);
  }
}

extern "C" void kernel_launch(void* const* d_in, const int* in_sizes, int n_in,
                              void* d_out, int out_size, void* d_ws, size_t ws_size,
                              hipStream_t stream) {
  const float* hidden = (const float*)d_in[0];
  const float* mask   = (const float*)d_in[1];
  const float* Wq     = (const float*)d_in[2];
  const float* Wk     = (const float*)d_in[3];
  const float* Wv     = (const float*)d_in[4];
  const float* Wo     = (const float*)d_in[5];
  float* out = (float*)d_out;

  char* ws = (char*)d_ws;
  unsigned short* BT  = (unsigned short*)(ws);                 // 3072x2048 bf16
  unsigned short* WoT = (unsigned short*)(ws + 12582912);      // 2048x2048 bf16
  unsigned short* Qb  = (unsigned short*)(ws + 20971520);      // [B][NH][S][HD]
  unsigned short* Kb  = (unsigned short*)(ws + 37748736);      // [B][NKV][S][HD]
  unsigned short* VT  = (unsigned short*)(ws + 41943040);      // [B][NKV][HD][S]
  unsigned short* AO  = (unsigned short*)(ws + 46137344);      // [MROWS][2048] bf16
  float*          tbl = (float*)(ws + 62914560);               // [S][64][2] f32
  float*          mkS = (float*)(ws + 63963136);               // [B][S] f32, pre-scaled
  unsigned short* Ab  = AO;  // hidden as bf16; dead before attn writes AO

  prep_all<<<dim3(14864), 256, 0, stream>>>(hidden, Wq, Wk, Wv, Wo, mask,
                                            Ab, BT, WoT, tbl, mkS);
  gemm_qkv<<<dim3(192), 512, 0, stream>>>(Ab, BT, tbl, Qb, Kb, VT);
  attn_fwd<<<dim3(1024), 256, 0, stream>>>(Qb, Kb, VT, mkS, AO);
  gemm_out<<<dim3(256), 512, 0, stream>>>(AO, WoT, out);
}

// Round 18
// 201.082 us; speedup vs baseline: 1.2176x; 1.0024x over previous
//
#include <hip/hip_runtime.h>
#include <hip/hip_bf16.h>

#define BATCH 2
#define SEQ   2048
#define NH    16
#define NKV   4
#define HD    128
#define KDIM  2048
#define MROWS 4096
#define NQKV  3072

typedef __attribute__((ext_vector_type(8))) short  s16x8;
typedef __attribute__((ext_vector_type(4))) short  s16x4;
typedef __attribute__((ext_vector_type(4))) float  f32x4;
typedef __attribute__((ext_vector_type(8))) __bf16 b16x8;

// barrier that drains LDS ops only -- leaves global prefetch loads in flight
#define BARRIER_LDS() do { \
    asm volatile("s_waitcnt lgkmcnt(0)" ::: "memory"); \
    __builtin_amdgcn_s_barrier(); \
  } while (0)

// barrier that drains this wave's outstanding global/DMA loads, then syncs
#define BARRIER_VM() do { \
    asm volatile("s_waitcnt vmcnt(0)" ::: "memory"); \
    __builtin_amdgcn_s_barrier(); \
  } while (0)

__device__ __forceinline__ unsigned short f2bf(float f) {
  __hip_bfloat16 h = __float2bfloat16(f);
  return *reinterpret_cast<unsigned short*>(&h);
}
__device__ __forceinline__ float bf2f(unsigned short h) {
  union { unsigned int u; float f; } x; x.u = ((unsigned int)h) << 16;
  return x.f;
}

// pack two f32 -> one u32 of two bf16 (TRUNCATION) in a single v_perm_b32
__device__ __forceinline__ unsigned pack2_trunc(float hif, float lof) {
  unsigned r, sel = 0x07060302u;
  asm("v_perm_b32 %0, %1, %2, %3" : "=v"(r) : "v"(hif), "v"(lof), "v"(sel));
  return r;
}
__device__ __forceinline__ float max3f(float a, float b, float c) {
  float r;
  asm("v_max3_f32 %0, %1, %2, %3" : "=v"(r) : "v"(a), "v"(b), "v"(c));
  return r;
}

__device__ __forceinline__ f32x4 MFMA16(s16x8 a, s16x8 b, f32x4 c) {
  return __builtin_amdgcn_mfma_f32_16x16x32_bf16(
      __builtin_bit_cast(b16x8, a), __builtin_bit_cast(b16x8, b), c, 0, 0, 0);
}

__device__ __forceinline__ void gload_lds16(const void* g, void* lds) {
  __builtin_amdgcn_global_load_lds(
      (const __attribute__((address_space(1))) void*)g,
      (__attribute__((address_space(3))) void*)lds, 16, 0, 0);
}

// ---------------- fused prep: hidden->bf16 + weight transposes + rope table + scaled mask ----------------
__global__ __launch_bounds__(256) void prep_all(
    const float* __restrict__ hidden,
    const float* __restrict__ Wq, const float* __restrict__ Wk,
    const float* __restrict__ Wv, const float* __restrict__ Wo,
    const float* __restrict__ mask,
    unsigned short* __restrict__ Ab, unsigned short* __restrict__ BT,
    unsigned short* __restrict__ WoT, float* __restrict__ tbl,
    float* __restrict__ maskS) {
  __shared__ float tile[32][33];
  int bid = blockIdx.x;
  if (bid < 10240) {
    int sub = bid % 160, ky = bid / 160;
    const float* W; unsigned short* WT; int Nd, nb;
    if (sub < 64)       { W = Wq; WT = BT;                       Nd = 2048; nb = sub; }
    else if (sub < 80)  { W = Wk; WT = BT + (size_t)2048 * KDIM; Nd = 512;  nb = sub - 64; }
    else if (sub < 96)  { W = Wv; WT = BT + (size_t)2560 * KDIM; Nd = 512;  nb = sub - 80; }
    else                { W = Wo; WT = WoT;                      Nd = 2048; nb = sub - 96; }
    int n0 = nb * 32, k0 = ky * 32;
    int tx = threadIdx.x & 31, ty = threadIdx.x >> 5;
#pragma unroll
    for (int i = 0; i < 4; ++i)
      tile[ty + i * 8][tx] = W[(size_t)(k0 + ty + i * 8) * Nd + n0 + tx];
    __syncthreads();
#pragma unroll
    for (int i = 0; i < 4; ++i)
      WT[(size_t)(n0 + ty + i * 8) * KDIM + k0 + tx] = f2bf(tile[tx][ty + i * 8]);
  } else if (bid < 14336) {
    int i = (bid - 10240) * 256 + threadIdx.x;
    const float4 a = ((const float4*)hidden)[2 * i];
    const float4 b = ((const float4*)hidden)[2 * i + 1];
    s16x8 o;
    o[0] = (short)f2bf(a.x); o[1] = (short)f2bf(a.y);
    o[2] = (short)f2bf(a.z); o[3] = (short)f2bf(a.w);
    o[4] = (short)f2bf(b.x); o[5] = (short)f2bf(b.y);
    o[6] = (short)f2bf(b.z); o[7] = (short)f2bf(b.w);
    ((s16x8*)Ab)[i] = o;
  } else if (bid < 14848) {
    int i = (bid - 14336) * 256 + threadIdx.x;
    int s = i >> 6, j = i & 63;
    float inv = powf(10000.0f, -(float)(2 * j) * (1.0f / 128.0f));
    float f = (float)s * inv;
    tbl[2 * i]     = cosf(f);
    tbl[2 * i + 1] = sinf(f);
  } else {
    int i = (bid - 14848) * 256 + threadIdx.x;
    maskS[i] = mask[i] * 1.44269504088896f;
  }
}

// ---------------- QKV GEMM v3: 256x256, BK=32, 4-deep ring, counted vmcnt, fused RoPE ----------------
__global__ __launch_bounds__(512, 2) void gemm_qkv(
    const unsigned short* __restrict__ A, const unsigned short* __restrict__ BT,
    const float* __restrict__ tbl,
    unsigned short* __restrict__ Qo, unsigned short* __restrict__ Ko,
    unsigned short* __restrict__ Vo) {
  __shared__ __align__(16) unsigned short lds_[66560];
#define RING(buf, ab) (lds_ + (((buf) * 2 + (ab)) << 13))
  int tid = threadIdx.x, lane = tid & 63;
  int w = tid >> 6, wm = w >> 2, wn = w & 3;
  int lin = blockIdx.x;
  int swz = (lin & 7) * 24 + (lin >> 3);
  int bx = swz % 12, by = swz / 12;
  int m0 = by * 256, n0 = bx * 256;
  int fr = lane & 15, cg4 = lane >> 4, rg4 = (lane >> 4) * 4;

  int rS1 = tid >> 2,        cS1 = (tid & 3) ^ (rS1 & 3);
  int t2  = tid + 512;
  int rS2 = t2 >> 2,         cS2 = (t2 & 3) ^ (rS2 & 3);

  f32x4 acc[8][4] = {};

#pragma unroll
  for (int kt = 0; kt < 2; ++kt) {
    gload_lds16(A + (size_t)(m0 + rS1) * KDIM + kt * 32 + cS1 * 8,
                (char*)RING(kt, 0) + (size_t)tid * 16);
    gload_lds16(A + (size_t)(m0 + rS2) * KDIM + kt * 32 + cS2 * 8,
                (char*)RING(kt, 0) + (size_t)t2 * 16);
    gload_lds16(BT + (size_t)(n0 + rS1) * KDIM + kt * 32 + cS1 * 8,
                (char*)RING(kt, 1) + (size_t)tid * 16);
    gload_lds16(BT + (size_t)(n0 + rS2) * KDIM + kt * 32 + cS2 * 8,
                (char*)RING(kt, 1) + (size_t)t2 * 16);
  }

  const int NK = KDIM / 32;
  for (int kt = 0; kt < NK; ++kt) {
    int buf = kt & 3;
    if (kt == NK - 1) asm volatile("s_waitcnt vmcnt(0)" ::: "memory");
    else              asm volatile("s_waitcnt vmcnt(4)" ::: "memory");
    __builtin_amdgcn_s_barrier();

    const unsigned short* lA = RING(buf, 0);
    const unsigned short* lB = RING(buf, 1);
    s16x8 bfr[4], afr[4];
#pragma unroll
    for (int nf = 0; nf < 4; ++nf) {
      int rb = wn * 64 + nf * 16 + fr;
      bfr[nf] = *(const s16x8*)(lB + rb * 32 + (cg4 ^ (rb & 3)) * 8);
    }
#pragma unroll
    for (int mf = 0; mf < 4; ++mf) {
      int ra = wm * 128 + mf * 16 + fr;
      afr[mf] = *(const s16x8*)(lA + ra * 32 + (cg4 ^ (ra & 3)) * 8);
    }
    if (kt + 2 < NK) {
      int nb = (kt + 2) & 3, ko = (kt + 2) * 32;
      gload_lds16(A + (size_t)(m0 + rS1) * KDIM + ko + cS1 * 8,
                  (char*)RING(nb, 0) + (size_t)tid * 16);
      gload_lds16(A + (size_t)(m0 + rS2) * KDIM + ko + cS2 * 8,
                  (char*)RING(nb, 0) + (size_t)t2 * 16);
    }
    __builtin_amdgcn_s_setprio(1);
#pragma unroll
    for (int mf = 0; mf < 4; ++mf)
#pragma unroll
      for (int nf = 0; nf < 4; ++nf)
        acc[mf][nf] = MFMA16(afr[mf], bfr[nf], acc[mf][nf]);
    __builtin_amdgcn_s_setprio(0);
#pragma unroll
    for (int mf = 0; mf < 4; ++mf) {
      int ra = wm * 128 + (mf + 4) * 16 + fr;
      afr[mf] = *(const s16x8*)(lA + ra * 32 + (cg4 ^ (ra & 3)) * 8);
    }
    if (kt + 2 < NK) {
      int nb = (kt + 2) & 3, ko = (kt + 2) * 32;
      gload_lds16(BT + (size_t)(n0 + rS1) * KDIM + ko + cS1 * 8,
                  (char*)RING(nb, 1) + (size_t)tid * 16);
      gload_lds16(BT + (size_t)(n0 + rS2) * KDIM + ko + cS2 * 8,
                  (char*)RING(nb, 1) + (size_t)t2 * 16);
    }
    __builtin_amdgcn_s_setprio(1);
#pragma unroll
    for (int mf = 0; mf < 4; ++mf)
#pragma unroll
      for (int nf = 0; nf < 4; ++nf)
        acc[mf + 4][nf] = MFMA16(afr[mf], bfr[nf], acc[mf + 4][nf]);
    __builtin_amdgcn_s_setprio(0);
  }

  if (bx < 10) {
    BARRIER_LDS();
    unsigned short* sc_ = lds_;
#pragma unroll
    for (int mf = 0; mf < 8; ++mf)
#pragma unroll
      for (int nf = 0; nf < 4; ++nf)
#pragma unroll
        for (int r = 0; r < 4; ++r)
          sc_[(wm * 128 + mf * 16 + rg4 + r) * 260 + wn * 64 + nf * 16 + fr] =
              f2bf(acc[mf][nf][r]);
    BARRIER_LDS();

#pragma unroll
    for (int i = 0; i < 8; ++i) {
      int t = tid + 512 * i;
      int row = t >> 4, rem = t & 15;
      int hl = rem >> 3, j0 = (rem & 7) * 8;
      int grow = m0 + row, bb = grow >> 11, ss = grow & 2047;
      const unsigned short* xb = sc_ + row * 260 + hl * 128;
      s16x8 xj  = *(const s16x8*)(xb + j0);
      s16x8 xj6 = *(const s16x8*)(xb + 64 + j0);
      s16x8 x2a = *(const s16x8*)(xb + 2 * j0);
      s16x8 x2b = *(const s16x8*)(xb + 2 * j0 + 8);
      const float* tb = tbl + ((size_t)ss * 64 + j0) * 2;
      union { float4 v[4]; float a[16]; } cs;
      cs.v[0] = *(const float4*)(tb);
      cs.v[1] = *(const float4*)(tb + 4);
      cs.v[2] = *(const float4*)(tb + 8);
      cs.v[3] = *(const float4*)(tb + 12);
      s16x8 o0, o1;
#pragma unroll
      for (int k = 0; k < 8; ++k) {
        float c  = cs.a[2 * k];
        float sn = cs.a[2 * k + 1];
        float xjf  = bf2f((unsigned short)xj[k]);
        float xj6f = bf2f((unsigned short)xj6[k]);
        float x2j  = (2 * k < 8) ? bf2f((unsigned short)x2a[2 * k])
                                 : bf2f((unsigned short)x2b[2 * k - 8]);
        float x2j1 = (2 * k + 1 < 8) ? bf2f((unsigned short)x2a[2 * k + 1])
                                     : bf2f((unsigned short)x2b[2 * k + 1 - 8]);
        o0[k] = (short)f2bf(xjf * c - x2j1 * sn);
        o1[k] = (short)f2bf(xj6f * c + x2j * sn);
      }
      unsigned short* dstp;
      if (bx < 8) {
        int hh = bx * 2 + hl;
        dstp = Qo + ((size_t)(bb * NH + hh) * SEQ + ss) * HD;
      } else {
        int kvh = (bx - 8) * 2 + hl;
        dstp = Ko + ((size_t)(bb * NKV + kvh) * SEQ + ss) * HD;
      }
      *(s16x8*)(dstp + j0)      = o0;
      *(s16x8*)(dstp + 64 + j0) = o1;
    }
  } else {
    int rbase = m0 + wm * 128 + rg4;
#pragma unroll
    for (int nf = 0; nf < 4; ++nf) {
      int gn = n0 + wn * 64 + nf * 16 + fr;
      int c = gn - 2560, kvh = c >> 7, d = c & 127;
#pragma unroll
      for (int mf = 0; mf < 8; ++mf) {
        int grow0 = rbase + mf * 16;
        int bb = grow0 >> 11, ss = grow0 & 2047;
        s16x4 pk;
#pragma unroll
        for (int r = 0; r < 4; ++r) pk[r] = (short)f2bf(acc[mf][nf][r]);
        *(s16x4*)(Vo + ((size_t)(bb * NKV + kvh) * HD + d) * SEQ + ss) = pk;
      }
    }
  }
#undef RING
}

// ---------------- O-proj GEMM v2: 256x128 tile, BK=32, 4-deep ring, counted vmcnt ----------------
__global__ __launch_bounds__(512, 1) void gemm_out(
    const unsigned short* __restrict__ A, const unsigned short* __restrict__ BT,
    float* __restrict__ C) {
  __shared__ __align__(16) unsigned short ldsA[4][8192];
  __shared__ __align__(16) unsigned short ldsB[4][4096];
  int tid = threadIdx.x, lane = tid & 63;
  int w = tid >> 6, wm = w >> 2, wn = w & 3;
  int lin = blockIdx.x;
  int swz = (lin & 7) * 32 + (lin >> 3);
  int bx = swz % 16, by = swz / 16;
  int m0 = by * 256, n0 = bx * 128;
  int fr = lane & 15, cg4 = lane >> 4, rg4 = (lane >> 4) * 4;

  int rS1 = tid >> 2,  cS1 = (tid & 3) ^ (rS1 & 3);
  int t2  = tid + 512;
  int rS2 = t2 >> 2,   cS2 = (t2 & 3) ^ (rS2 & 3);
  int rB  = tid >> 2,  cB  = (tid & 3) ^ (rB & 3);

  f32x4 acc[8][2] = {};

#pragma unroll
  for (int kt = 0; kt < 2; ++kt) {
    gload_lds16(A + (size_t)(m0 + rS1) * KDIM + kt * 32 + cS1 * 8,
                (char*)&ldsA[kt][0] + (size_t)tid * 16);
    gload_lds16(A + (size_t)(m0 + rS2) * KDIM + kt * 32 + cS2 * 8,
                (char*)&ldsA[kt][0] + (size_t)t2 * 16);
    gload_lds16(BT + (size_t)(n0 + rB) * KDIM + kt * 32 + cB * 8,
                (char*)&ldsB[kt][0] + (size_t)tid * 16);
  }

  const int NK = KDIM / 32;
  for (int kt = 0; kt < NK; ++kt) {
    int buf = kt & 3;
    if (kt == NK - 1) asm volatile("s_waitcnt vmcnt(0)" ::: "memory");
    else              asm volatile("s_waitcnt vmcnt(3)" ::: "memory");
    __builtin_amdgcn_s_barrier();

    const unsigned short* lA = &ldsA[buf][0];
    const unsigned short* lB = &ldsB[buf][0];
    s16x8 bfr[2], afr[4];
#pragma unroll
    for (int nf = 0; nf < 2; ++nf) {
      int rb = wn * 32 + nf * 16 + fr;
      bfr[nf] = *(const s16x8*)(lB + rb * 32 + (cg4 ^ (rb & 3)) * 8);
    }
#pragma unroll
    for (int mf = 0; mf < 4; ++mf) {
      int ra = wm * 128 + mf * 16 + fr;
      afr[mf] = *(const s16x8*)(lA + ra * 32 + (cg4 ^ (ra & 3)) * 8);
    }
    if (kt + 2 < NK) {
      int nb = (kt + 2) & 3, ko = (kt + 2) * 32;
      gload_lds16(A + (size_t)(m0 + rS1) * KDIM + ko + cS1 * 8,
                  (char*)&ldsA[nb][0] + (size_t)tid * 16);
      gload_lds16(A + (size_t)(m0 + rS2) * KDIM + ko + cS2 * 8,
                  (char*)&ldsA[nb][0] + (size_t)t2 * 16);
    }
    __builtin_amdgcn_s_setprio(1);
#pragma unroll
    for (int mf = 0; mf < 4; ++mf)
#pragma unroll
      for (int nf = 0; nf < 2; ++nf)
        acc[mf][nf] = MFMA16(afr[mf], bfr[nf], acc[mf][nf]);
    __builtin_amdgcn_s_setprio(0);
#pragma unroll
    for (int mf = 0; mf < 4; ++mf) {
      int ra = wm * 128 + (mf + 4) * 16 + fr;
      afr[mf] = *(const s16x8*)(lA + ra * 32 + (cg4 ^ (ra & 3)) * 8);
    }
    if (kt + 2 < NK) {
      int nb = (kt + 2) & 3, ko = (kt + 2) * 32;
      gload_lds16(BT + (size_t)(n0 + rB) * KDIM + ko + cB * 8,
                  (char*)&ldsB[nb][0] + (size_t)tid * 16);
    }
    __builtin_amdgcn_s_setprio(1);
#pragma unroll
    for (int mf = 0; mf < 4; ++mf)
#pragma unroll
      for (int nf = 0; nf < 2; ++nf)
        acc[mf + 4][nf] = MFMA16(afr[mf], bfr[nf], acc[mf + 4][nf]);
    __builtin_amdgcn_s_setprio(0);
  }

  int rbase = m0 + wm * 128 + rg4;
#pragma unroll
  for (int nf = 0; nf < 2; ++nf) {
    int gn = n0 + wn * 32 + nf * 16 + fr;
#pragma unroll
    for (int mf = 0; mf < 8; ++mf)
#pragma unroll
      for (int r = 0; r < 4; ++r)
        C[(size_t)(rbase + mf * 16 + r) * 2048 + gn] = acc[mf][nf][r];
  }
}

// ---------------- Flash attention v15: gload_lds-staged K/V dbuf, vmcnt fence ----------------
// K tile [64][128] bf16 (16 chunks/row, source-XOR cs^ (r&15));
// V tile [128][64] (8 chunks/row, cs ^ (d&7)). One vmcnt(0)+barrier per round.
__global__ __launch_bounds__(256, 2) void attn_fwd(
    const unsigned short* __restrict__ Q, const unsigned short* __restrict__ K,
    const unsigned short* __restrict__ VT, const float* __restrict__ maskS,
    unsigned short* __restrict__ O) {
  __shared__ __align__(16) unsigned short kt_[2][64 * 128];
  __shared__ __align__(16) unsigned short vt_[2][128 * 64];
  __shared__ __align__(16) unsigned short pt_[4][16][36];

  int tid = threadIdx.x, lane = tid & 63, w = tid >> 6;
  int l = blockIdx.x;
  int grp = l & 7, slot = l >> 3;
  int hloc = slot & 3, qt = 31 - (slot >> 2);
  int b = grp >> 2, kvh = grp & 3, h = kvh * 4 + hloc;
  int qbase = qt * 64;
  int qw = qbase + w * 16;
  int fr = lane & 15, g = lane >> 4, kg = g * 8, rg = g * 4;

  const unsigned short* Qb = Q + (size_t)(b * NH + h) * SEQ * HD;
  const unsigned short* Kb = K + (size_t)(b * NKV + kvh) * SEQ * HD;
  const unsigned short* Vb = VT + (size_t)(b * NKV + kvh) * HD * SEQ;
  const float* mb = maskS + (size_t)b * SEQ;   // pre-scaled by log2(e)

  const float sc2 = 0.12751744584812722f;      // 1/sqrt(128) * log2(e)
  int bS = b * SEQ;
  int ntiles = qt + 1;

  s16x8 aq[4];
#pragma unroll
  for (int dc = 0; dc < 4; ++dc)
    aq[dc] = *(const s16x8*)(Qb + (size_t)(qw + fr) * HD + dc * 32 + kg);

  f32x4 oacc[8] = {};
  float m_r = -3e38f, l_r = 0.f;

  // prologue: DMA tile 0 into buf 0
#pragma unroll
  for (int i = 0; i < 4; ++i) {           // K: slot s -> row s>>4, chunk s&15
    int s = tid + 256 * i;
    int r = s >> 4, cg = (s & 15) ^ (r & 15);
    gload_lds16(Kb + (size_t)r * HD + cg * 8, (char*)&kt_[0][0] + (size_t)s * 16);
  }
#pragma unroll
  for (int i = 0; i < 4; ++i) {           // V: slot s -> row s>>3, chunk s&7
    int s = tid + 256 * i;
    int d = s >> 3, cg = (s & 7) ^ (d & 7);
    gload_lds16(Vb + (size_t)d * SEQ + cg * 8, (char*)&vt_[0][0] + (size_t)s * 16);
  }
  BARRIER_VM();

  for (int t = 0; t < ntiles; ++t) {
    int kv0 = t * 64;
    int cur = t & 1;
    bool diag = (t == qt);

    // issue tile t+1 DMA into buf[cur^1]; waits at end-of-round fence
    if (t + 1 < ntiles) {
#pragma unroll
      for (int i = 0; i < 4; ++i) {
        int s = tid + 256 * i;
        int r = s >> 4, cg = (s & 15) ^ (r & 15);
        gload_lds16(Kb + (size_t)(kv0 + 64 + r) * HD + cg * 8,
                    (char*)&kt_[cur ^ 1][0] + (size_t)s * 16);
      }
#pragma unroll
      for (int i = 0; i < 4; ++i) {
        int s = tid + 256 * i;
        int d = s >> 3, cg = (s & 7) ^ (d & 7);
        gload_lds16(Vb + (size_t)d * SEQ + kv0 + 64 + cg * 8,
                    (char*)&vt_[cur ^ 1][0] + (size_t)s * 16);
      }
    }

    // QK^T: S^T element (kv = kv0+mk*16+rg+r, q = qw+fr); K chunk swz = (dc*4+g)^fr
    f32x4 sf[4];
    __builtin_amdgcn_s_setprio(1);
#pragma unroll
    for (int mk = 0; mk < 4; ++mk) {
      s16x8 ak[4];
#pragma unroll
      for (int dc = 0; dc < 4; ++dc)
        ak[dc] = *(const s16x8*)(&kt_[cur][((mk * 16 + fr) * 16 + ((dc * 4 + g) ^ fr)) * 8]);
      sf[mk] = f32x4{0.f, 0.f, 0.f, 0.f};
#pragma unroll
      for (int dc = 0; dc < 4; ++dc)
        sf[mk] = MFMA16(ak[dc], aq[dc], sf[mk]);
    }
    __builtin_amdgcn_s_setprio(0);

    // scale + pre-scaled mask; causal select only on diagonal tile
#pragma unroll
    for (int mk = 0; mk < 4; ++mk) {
      float4 mv = *(const float4*)(mb + kv0 + mk * 16 + rg);
      float mvr[4] = {mv.x, mv.y, mv.z, mv.w};
      if (diag) {
#pragma unroll
        for (int r = 0; r < 4; ++r) {
          int kv = kv0 + mk * 16 + rg + r;
          float v = sf[mk][r] * sc2 + mvr[r];
          sf[mk][r] = (kv <= qw + fr) ? v : -3e38f;
        }
      } else {
#pragma unroll
        for (int r = 0; r < 4; ++r)
          sf[mk][r] = sf[mk][r] * sc2 + mvr[r];
      }
    }

    // online softmax (exp2 domain); max3 tree
    float m0_ = max3f(sf[0][0], sf[0][1], sf[0][2]);
    float m1_ = max3f(sf[0][3], sf[1][0], sf[1][1]);
    float m2_ = max3f(sf[1][2], sf[1][3], sf[2][0]);
    float m3_ = max3f(sf[2][1], sf[2][2], sf[2][3]);
    float m4_ = max3f(sf[3][0], sf[3][1], sf[3][2]);
    float ma_ = max3f(m0_, m1_, m2_);
    float mb_ = max3f(m3_, m4_, sf[3][3]);
    float pm = fmaxf(ma_, mb_);
    pm = fmaxf(pm, __shfl_xor(pm, 16, 64));
    pm = fmaxf(pm, __shfl_xor(pm, 32, 64));
    if (!__all(pm - m_r <= 8.0f)) {
      float mo = m_r;
      float mn = fmaxf(mo, pm);
      float al = exp2f(mo - mn);
      m_r = mn;
      l_r *= al;
#pragma unroll
      for (int r = 0; r < 4; ++r) {
        float ar = __shfl(al, rg + r, 16);
#pragma unroll
        for (int od = 0; od < 8; ++od) oacc[od][r] *= ar;
      }
    }
    // exp2 + pairwise-tree sum
    float e[16];
#pragma unroll
    for (int mk = 0; mk < 4; ++mk)
#pragma unroll
      for (int r = 0; r < 4; ++r) {
        float ppv = exp2f(sf[mk][r] - m_r);
        sf[mk][r] = ppv;
        e[mk * 4 + r] = ppv;
      }
    float s0 = (e[0] + e[1]) + (e[2] + e[3]);
    float s1 = (e[4] + e[5]) + (e[6] + e[7]);
    float s2 = (e[8] + e[9]) + (e[10] + e[11]);
    float s3 = (e[12] + e[13]) + (e[14] + e[15]);
    float rs = (s0 + s1) + (s2 + s3);
    rs += __shfl_xor(rs, 16, 64);
    rs += __shfl_xor(rs, 32, 64);
    l_r += rs;

    // PV: P -> pt_ via perm-pack; V chunk swz = (kk*4+g)^(fr&7)
#pragma unroll
    for (int kk = 0; kk < 2; ++kk) {
#pragma unroll
      for (int mh = 0; mh < 2; ++mh) {
        int mk = kk * 2 + mh;
        unsigned w0 = pack2_trunc(sf[mk][1], sf[mk][0]);
        unsigned w1 = pack2_trunc(sf[mk][3], sf[mk][2]);
        uint2 pk2; pk2.x = w0; pk2.y = w1;
        *(uint2*)(&pt_[w][fr][mh * 16 + rg]) = pk2;
      }
      s16x8 ap = *(const s16x8*)(&pt_[w][fr][kg]);
      __builtin_amdgcn_s_setprio(1);
#pragma unroll
      for (int od = 0; od < 8; ++od) {
        s16x8 bv = *(const s16x8*)(
            &vt_[cur][((od * 16 + fr) * 8 + ((kk * 4 + g) ^ (fr & 7))) * 8]);
        oacc[od] = MFMA16(ap, bv, oacc[od]);
      }
      __builtin_amdgcn_s_setprio(0);
    }

    BARRIER_VM();  // tile t+1 DMA retired (cross-wave via barrier); buf[cur] reads done
  }

  float iv = 1.0f / l_r;
  float ivr[4];
#pragma unroll
  for (int r = 0; r < 4; ++r) ivr[r] = __shfl(iv, rg + r, 16);
#pragma unroll
  for (int r = 0; r < 4; ++r) {
    unsigned short* op = O + (size_t)(bS + qw + rg + r) * 2048 + h * 128 + fr;
#pragma unroll
    for (int od = 0; od < 8; ++od)
      op[od * 16] = f2bf(oacc[od][r] * ivr[r]);
  }
}

extern "C" void kernel_launch(void* const* d_in, const int* in_sizes, int n_in,
                              void* d_out, int out_size, void* d_ws, size_t ws_size,
                              hipStream_t stream) {
  const float* hidden = (const float*)d_in[0];
  const float* mask   = (const float*)d_in[1];
  const float* Wq     = (const float*)d_in[2];
  const float* Wk     = (const float*)d_in[3];
  const float* Wv     = (const float*)d_in[4];
  const float* Wo     = (const float*)d_in[5];
  float* out = (float*)d_out;

  char* ws = (char*)d_ws;
  unsigned short* BT  = (unsigned short*)(ws);                 // 3072x2048 bf16
  unsigned short* WoT = (unsigned short*)(ws + 12582912);      // 2048x2048 bf16
  unsigned short* Qb  = (unsigned short*)(ws + 20971520);      // [B][NH][S][HD]
  unsigned short* Kb  = (unsigned short*)(ws + 37748736);      // [B][NKV][S][HD]
  unsigned short* VT  = (unsigned short*)(ws + 41943040);      // [B][NKV][HD][S]
  unsigned short* AO  = (unsigned short*)(ws + 46137344);      // [MROWS][2048] bf16
  float*          tbl = (float*)(ws + 62914560);               // [S][64][2] f32
  float*          mkS = (float*)(ws + 63963136);               // [B][S] f32, pre-scaled
  unsigned short* Ab  = AO;

  prep_all<<<dim3(14864), 256, 0, stream>>>(hidden, Wq, Wk, Wv, Wo, mask,
                                            Ab, BT, WoT, tbl, mkS);
  gemm_qkv<<<dim3(192), 512, 0, stream>>>(Ab, BT, tbl, Qb, Kb, VT);
  attn_fwd<<<dim3(1024), 256, 0, stream>>>(Qb, Kb, VT, mkS, AO);
  gemm_out<<<dim3(256), 512, 0, stream>>>(AO, WoT, out);
}